// Round 1
// baseline (17688.197 us; speedup 1.0000x reference)
//
#include <hip/hip_runtime.h>

// ---------------------------------------------------------------------------
// Decoder_60868276519063: attention-LSTM decoder forward (loss, acc)
// B=32 T=800 E=512 D=1024 V=5000 L=149 (150 steps) A=512
// Strategy: persistent sequential-loop kernel with hand-rolled grid barriers
// (3/step), MFMA bf16 GEMVs, batched prologue (pe, eyproj) + epilogue (CE).
// ---------------------------------------------------------------------------

typedef unsigned short u16;
typedef float f32x4 __attribute__((ext_vector_type(4)));
typedef short s16x8 __attribute__((ext_vector_type(8)));

constexpr int cB = 32, cT = 800, cE = 512, cD = 1024, cV = 5000, cL = 149,
              cNS = 150, cA = 512;
constexpr int SOS = 1, EOS = 2;
constexpr int NBLK = 256;   // persistent-kernel grid (1 block/CU co-resident)

__device__ __forceinline__ float bf2f(u16 x){
  union { unsigned u; float f; } v; v.u = ((unsigned)x) << 16; return v.f;
}
__device__ __forceinline__ u16 f2bf(float f){
  union { float f; unsigned u; } v; v.f = f;
  unsigned r = v.u + 0x7FFFu + ((v.u >> 16) & 1u);
  return (u16)(r >> 16);
}
__device__ __forceinline__ float fsigm(float x){ return 1.f / (1.f + __expf(-x)); }
__device__ __forceinline__ float ftanh(float x){
  float u = __expf(-2.f * fabsf(x));
  float t = (1.f - u) / (1.f + u);
  return (x < 0.f) ? -t : t;
}
__device__ __forceinline__ f32x4 MFMA(s16x8 a, s16x8 b, f32x4 c){
  return __builtin_amdgcn_mfma_f32_16x16x32_bf16(a, b, c, 0, 0, 0);
}
__device__ __forceinline__ s16x8 LD8(const u16* p){ return *(const s16x8*)p; }

// ------------------------------- prologue ----------------------------------
__global__ void k_init(int* bar, float* q, float* c0, float* c1, u16* z1slot0){
  int i = blockIdx.x * blockDim.x + threadIdx.x, n = gridDim.x * blockDim.x;
  for (int k = i; k < 2048; k += n) bar[k] = 0;
  for (int k = i; k < cB * cA; k += n) q[k] = 0.f;
  for (int k = i; k < 2 * cB * cD; k += n){ c0[k] = 0.f; c1[k] = 0.f; }
  for (int k = i; k < cB * cD; k += n) z1slot0[k] = 0;
}

__global__ void k_cvt(const float* __restrict__ s, u16* __restrict__ d, int n4){
  int i = blockIdx.x * blockDim.x + threadIdx.x, st = gridDim.x * blockDim.x;
  for (int k = i; k < n4; k += st){
    float4 v = ((const float4*)s)[k];
    ushort4 o; o.x = f2bf(v.x); o.y = f2bf(v.y); o.z = f2bf(v.z); o.w = f2bf(v.w);
    ((ushort4*)d)[k] = o;
  }
}

// dst[r][c] = src[r][coff+c], cols = 1<<cshift
__global__ void k_slice(const float* __restrict__ s, u16* __restrict__ d, int n,
                        int cshift, int srcld, int coff){
  int i = blockIdx.x * blockDim.x + threadIdx.x, st = gridDim.x * blockDim.x;
  int cmask = (1 << cshift) - 1;
  for (int k = i; k < n; k += st){
    int r = k >> cshift, c = k & cmask;
    d[k] = f2bf(s[(size_t)r * srcld + coff + c]);
  }
}

// dst [rows_out][cols_out] with cols_out = 1<<rshift; dst[a][dd]=src[dd][a]
__global__ void k_transp(const float* __restrict__ s, u16* __restrict__ d, int n,
                         int rshift, int csrc){
  int i = blockIdx.x * blockDim.x + threadIdx.x, st = gridDim.x * blockDim.x;
  int mask = (1 << rshift) - 1;
  for (int k = i; k < n; k += st){
    int dd = k & mask, a = k >> rshift;
    d[k] = f2bf(s[(size_t)dd * csrc + a]);
  }
}

__global__ void k_bias(const float* a, const float* b, float* o, int n){
  int i = blockIdx.x * blockDim.x + threadIdx.x, st = gridDim.x * blockDim.x;
  for (int k = i; k < n; k += st) o[k] = a[k] + b[k];
}

// pe[b*T+t][a] = hpad_row @ W_encT_row   (mask not needed: t>=hlen unused)
__global__ __launch_bounds__(256) void k_pe(const u16* __restrict__ hpadM,
                                            const u16* __restrict__ WencT,
                                            u16* __restrict__ pe){
  int tid = threadIdx.x, w = tid >> 6, l = tid & 63;
  int mt = blockIdx.x * 4 + w;           // 1600 mtiles of 16 rows
  int m0 = mt * 16;
  int kin = 8 * (l >> 4), col = l & 15;
  const u16* xrow = hpadM + (size_t)(m0 + col) * cE;
  for (int ng = 0; ng < 4; ++ng){
    f32x4 acc[8] = {};
    for (int kc = 0; kc < 16; ++kc){
      int k = kc * 32 + kin;
      s16x8 a = LD8(xrow + k);
      #pragma unroll
      for (int nt = 0; nt < 8; ++nt){
        const u16* wr = WencT + (size_t)((ng * 8 + nt) * 16 + col) * cE + k;
        acc[nt] = MFMA(a, LD8(wr), acc[nt]);
      }
    }
    #pragma unroll
    for (int nt = 0; nt < 8; ++nt){
      int a0 = (ng * 8 + nt) * 16 + col;
      #pragma unroll
      for (int r = 0; r < 4; ++r){
        int row = m0 + (l >> 4) * 4 + r;
        pe[(size_t)row * cA + a0] = f2bf(acc[nt][r]);
      }
    }
  }
}

// eyproj[s*32+b][j] = embed[ys_in] @ W_ih0[:, :1024]^T + b_ih0 + b_hh0
// also writes g0buf parity0 for step 0 (hh0(0) = 0)
__global__ __launch_bounds__(256) void k_eyproj(const u16* __restrict__ embb,
    const int* __restrict__ ys, const u16* __restrict__ Wih0m,
    const float* __restrict__ bih0, const float* __restrict__ bhh0,
    u16* __restrict__ eyproj, float* __restrict__ g0buf){
  int tid = threadIdx.x, w = tid >> 6, l = tid & 63;
  int mt = blockIdx.x * 4 + w;           // 300 mtiles
  int m0 = mt * 16;
  int kin = 8 * (l >> 4), col = l & 15;
  int r = m0 + col;
  int s = r >> 5, b = r & 31;
  int tok = (s == 0) ? SOS : ys[b * cL + (s - 1)];
  const u16* xrow = embb + (size_t)tok * cD;
  for (int ng = 0; ng < 32; ++ng){
    f32x4 acc[8] = {};
    for (int kc = 0; kc < 32; ++kc){
      int k = kc * 32 + kin;
      s16x8 a = LD8(xrow + k);
      #pragma unroll
      for (int nt = 0; nt < 8; ++nt){
        const u16* wr = Wih0m + (size_t)((ng * 8 + nt) * 16 + col) * cD + k;
        acc[nt] = MFMA(a, LD8(wr), acc[nt]);
      }
    }
    #pragma unroll
    for (int nt = 0; nt < 8; ++nt){
      int j = (ng * 8 + nt) * 16 + col;
      float bj = bih0[j] + bhh0[j];
      #pragma unroll
      for (int rr = 0; rr < 4; ++rr){
        int row = m0 + (l >> 4) * 4 + rr;
        float val = acc[nt][rr] + bj;
        eyproj[(size_t)row * 4096 + j] = f2bf(val);
        if (row < 32) g0buf[row * 4096 + j] = val;   // s==0 rows
      }
    }
  }
}

// ------------------------------ main loop ----------------------------------
struct LoopArgs {
  const int* hlen;
  const u16* pe; const u16* hpadM; const u16* eyproj;
  const u16* WdecT; const u16* Waatt; const u16* Whh0; const u16* Wih1; const u16* Whh1;
  const float* vatt; const float* bias01;
  float* q; float* stats; u16* acpart; float* g0buf; float* hh1buf; u16* z0p;
  float* c0; float* c1; u16* z1all;
  int* bar;
};

struct PaLds { float e_sh[128]; float wmax[8]; float red[8]; };
struct PbLds { u16 att[32 * 520]; float scale[256]; float acc[8][2][16][16]; };
struct PcLds { float acc[8][2][16][16]; };
union LoopLds { PaLds pa; PbLds pb; PcLds pc; };

__device__ __forceinline__ void gbar(int* bar, int idx){
  __syncthreads();
  if (threadIdx.x == 0){
    __threadfence();   // release this block's writes (agent scope)
    int v = __hip_atomic_fetch_add(&bar[2 * idx], 1, __ATOMIC_RELAXED,
                                   __HIP_MEMORY_SCOPE_AGENT);
    if (v == NBLK - 1){
      __hip_atomic_store(&bar[2 * idx + 1], 1, __ATOMIC_RELAXED,
                         __HIP_MEMORY_SCOPE_AGENT);
    } else {
      while (__hip_atomic_load(&bar[2 * idx + 1], __ATOMIC_RELAXED,
                               __HIP_MEMORY_SCOPE_AGENT) == 0)
        __builtin_amdgcn_s_sleep(2);
    }
    __threadfence();   // acquire: invalidate stale caches
  }
  __syncthreads();
}

__global__ __launch_bounds__(512) void k_loop(LoopArgs g_){
  __shared__ LoopLds lds;
  const int blk = blockIdx.x, tid = threadIdx.x;
  const int w = tid >> 6, l = tid & 63;
  const int kin = 8 * (l >> 4), col = l & 15;
  int bi = 0;
  for (int s = 0; s < cNS; ++s){
    const int p = s & 1;
    // ============ PA: attention partials (all 256 blocks: b x oct) =========
    {
      const int b = blk >> 3, oct = blk & 7;
      const int t0 = oct * 100;
      const int hl = g_.hlen[b];
      const int t1 = (t0 + 100 < hl) ? t0 + 100 : hl;
      float qv[8], vv[8];
      #pragma unroll
      for (int i = 0; i < 8; ++i){
        qv[i] = g_.q[b * cA + l * 8 + i];
        vv[i] = g_.vatt[l * 8 + i];
      }
      float lmax = -1e30f;
      for (int t = t0 + w; t < t1; t += 8){
        const u16* per = g_.pe + ((size_t)b * cT + t) * cA + l * 8;
        s16x8 pv = LD8(per);
        float sum = 0.f;
        #pragma unroll
        for (int i = 0; i < 8; ++i){
          float x = bf2f((u16)pv[i]) + qv[i];
          sum += vv[i] * ftanh(x);
        }
        #pragma unroll
        for (int m = 1; m < 64; m <<= 1) sum += __shfl_xor(sum, m, 64);
        if (l == 0) lds.pa.e_sh[t - t0] = sum;
        lmax = fmaxf(lmax, sum);
      }
      if (l == 0) lds.pa.wmax[w] = lmax;
      __syncthreads();
      float cmax = -1e30f;
      #pragma unroll
      for (int i = 0; i < 8; ++i) cmax = fmaxf(cmax, lds.pa.wmax[i]);
      const int cnt = t1 - t0;
      float myw = 0.f;
      if (tid < cnt){
        myw = __expf(lds.pa.e_sh[tid] - cmax);
        lds.pa.e_sh[tid] = myw;      // only this thread touches slot tid
      }
      float ssum = myw;
      #pragma unroll
      for (int m = 1; m < 64; m <<= 1) ssum += __shfl_xor(ssum, m, 64);
      if (l == 0) lds.pa.red[w] = ssum;
      __syncthreads();
      if (tid == 0){
        float csum = 0.f;
        #pragma unroll
        for (int i = 0; i < 8; ++i) csum += lds.pa.red[i];
        g_.stats[(b * 8 + oct) * 2 + 0] = cmax;
        g_.stats[(b * 8 + oct) * 2 + 1] = csum;
      }
      if (cnt > 0){
        float acc = 0.f;
        const int e = w * 64 + l;
        const u16* hp = g_.hpadM + ((size_t)b * cT + t0) * cE + e;
        for (int t = 0; t < cnt; ++t)
          acc = fmaf(lds.pa.e_sh[t], bf2f(hp[(size_t)t * cE]), acc);
        g_.acpart[((size_t)b * 8 + oct) * cE + e] = f2bf(acc);
      }
    }
    gbar(g_.bar, bi++);
    // ============ PB ======================================================
    if (blk < 64){
      // ---- softmax combine -> att_c (redundant per block, into LDS) ----
      if (tid < 256){
        int b2 = tid >> 3, o = tid & 7;
        float gm = -1e30f;
        #pragma unroll
        for (int o2 = 0; o2 < 8; ++o2)
          gm = fmaxf(gm, g_.stats[(b2 * 8 + o2) * 2]);
        float gs = 0.f;
        #pragma unroll
        for (int o2 = 0; o2 < 8; ++o2)
          gs += g_.stats[(b2 * 8 + o2) * 2 + 1] *
                __expf(g_.stats[(b2 * 8 + o2) * 2] - gm);
        lds.pb.scale[tid] = __expf(g_.stats[(b2 * 8 + o) * 2] - gm) / gs;
      }
      __syncthreads();
      for (int b2 = 0; b2 < 32; ++b2){
        float v = 0.f;
        #pragma unroll
        for (int o = 0; o < 8; ++o)
          v += lds.pb.scale[b2 * 8 + o] *
               bf2f(g_.acpart[((size_t)b2 * 8 + o) * cE + tid]);
        lds.pb.att[b2 * 520 + tid] = f2bf(v);
      }
      __syncthreads();
      // ---- g0 att-part: att_c @ Wa^T, wave = (gate, khalf) ----
      {
        const int g = w >> 1, kh = w & 1;
        const int j0 = g * 1024 + blk * 16;
        f32x4 a0 = {0.f,0.f,0.f,0.f}, a1 = {0.f,0.f,0.f,0.f};
        const u16* wrow = g_.Waatt + (size_t)(j0 + col) * cE;
        const u16* xr0 = &lds.pb.att[col * 520];
        const u16* xr1 = &lds.pb.att[(16 + col) * 520];
        for (int kc = 0; kc < 8; ++kc){
          int k = kh * 256 + kc * 32 + kin;
          s16x8 bf = LD8(wrow + k);
          a0 = MFMA(LD8(xr0 + k), bf, a0);
          a1 = MFMA(LD8(xr1 + k), bf, a1);
        }
        #pragma unroll
        for (int r = 0; r < 4; ++r){
          lds.pb.acc[w][0][(l >> 4) * 4 + r][col] = a0[r];
          lds.pb.acc[w][1][(l >> 4) * 4 + r][col] = a1[r];
        }
      }
      __syncthreads();
      // ---- LSTM0 pointwise ----
      {
        int b2 = tid >> 4, dc = tid & 15;
        int d = blk * 16 + dc;
        int mt = b2 >> 4, rr = b2 & 15;
        float gate[4];
        #pragma unroll
        for (int gg = 0; gg < 4; ++gg){
          gate[gg] = lds.pb.acc[gg * 2][mt][rr][dc] +
                     lds.pb.acc[gg * 2 + 1][mt][rr][dc] +
                     g_.g0buf[(size_t)p * cB * 4096 + b2 * 4096 + gg * 1024 + d];
        }
        float c = fsigm(gate[1]) * g_.c0[(size_t)p * cB * cD + b2 * cD + d] +
                  fsigm(gate[0]) * ftanh(gate[2]);
        float z = fsigm(gate[3]) * ftanh(c);
        g_.c0[(size_t)(p ^ 1) * cB * cD + b2 * cD + d] = c;
        g_.z0p[b2 * cD + d] = f2bf(z);
      }
    } else if (blk < 192){
      // ---- hh1 = z1(s-1) @ W_hh1^T + (b_ih1+b_hh1), wave = (nt, kq) ----
      const int jb = (blk - 64) * 32;
      const int nt = w >> 2, kq = w & 3;
      const int j0 = jb + nt * 16;
      const u16* z1s = g_.z1all + (size_t)s * cB * cD;   // slot s = z1(s-1)
      f32x4 a0 = {0.f,0.f,0.f,0.f}, a1 = {0.f,0.f,0.f,0.f};
      const u16* wrow = g_.Whh1 + (size_t)(j0 + col) * cD;
      const u16* xr0 = z1s + (size_t)col * cD;
      const u16* xr1 = z1s + (size_t)(16 + col) * cD;
      for (int kc = 0; kc < 8; ++kc){
        int k = kq * 256 + kc * 32 + kin;
        s16x8 bf = LD8(wrow + k);
        a0 = MFMA(LD8(xr0 + k), bf, a0);
        a1 = MFMA(LD8(xr1 + k), bf, a1);
      }
      #pragma unroll
      for (int r = 0; r < 4; ++r){
        lds.pc.acc[w][0][(l >> 4) * 4 + r][col] = a0[r];
        lds.pc.acc[w][1][(l >> 4) * 4 + r][col] = a1[r];
      }
      __syncthreads();
      #pragma unroll
      for (int it = 0; it < 2; ++it){
        int idx = it * 512 + tid;
        int b2 = idx >> 5, jj = idx & 31;
        int nt2 = jj >> 4, c2 = jj & 15;
        int mt = b2 >> 4, rr = b2 & 15;
        float v = 0.f;
        #pragma unroll
        for (int kq2 = 0; kq2 < 4; ++kq2) v += lds.pc.acc[nt2 * 4 + kq2][mt][rr][c2];
        int j = jb + jj;
        g_.hh1buf[b2 * 4096 + j] = v + g_.bias01[j];
      }
    }
    gbar(g_.bar, bi++);
    // ============ PC ======================================================
    if (blk < 64){
      // ---- g1 = z0' @ W_ih1^T + hh1 ; LSTM1 ----
      const int g = w >> 1, kh = w & 1;
      const int j0 = g * 1024 + blk * 16;
      f32x4 a0 = {0.f,0.f,0.f,0.f}, a1 = {0.f,0.f,0.f,0.f};
      const u16* wrow = g_.Wih1 + (size_t)(j0 + col) * cD;
      const u16* xr0 = g_.z0p + (size_t)col * cD;
      const u16* xr1 = g_.z0p + (size_t)(16 + col) * cD;
      for (int kc = 0; kc < 16; ++kc){
        int k = kh * 512 + kc * 32 + kin;
        s16x8 bf = LD8(wrow + k);
        a0 = MFMA(LD8(xr0 + k), bf, a0);
        a1 = MFMA(LD8(xr1 + k), bf, a1);
      }
      #pragma unroll
      for (int r = 0; r < 4; ++r){
        lds.pc.acc[w][0][(l >> 4) * 4 + r][col] = a0[r];
        lds.pc.acc[w][1][(l >> 4) * 4 + r][col] = a1[r];
      }
      __syncthreads();
      {
        int b2 = tid >> 4, dc = tid & 15;
        int d = blk * 16 + dc;
        int mt = b2 >> 4, rr = b2 & 15;
        float gate[4];
        #pragma unroll
        for (int gg = 0; gg < 4; ++gg){
          gate[gg] = lds.pc.acc[gg * 2][mt][rr][dc] +
                     lds.pc.acc[gg * 2 + 1][mt][rr][dc] +
                     g_.hh1buf[b2 * 4096 + gg * 1024 + d];
        }
        float c = fsigm(gate[1]) * g_.c1[(size_t)p * cB * cD + b2 * cD + d] +
                  fsigm(gate[0]) * ftanh(gate[2]);
        float z = fsigm(gate[3]) * ftanh(c);
        g_.c1[(size_t)(p ^ 1) * cB * cD + b2 * cD + d] = c;
        g_.z1all[((size_t)s + 1) * cB * cD + b2 * cD + d] = f2bf(z);
      }
    } else if (blk < 192){
      if (s < cNS - 1){
        // ---- g0buf[p^1] = z0' @ W_hh0^T + eyproj[s+1] ----
        const int jb = (blk - 64) * 32;
        const int nt = w >> 2, kq = w & 3;
        const int j0 = jb + nt * 16;
        f32x4 a0 = {0.f,0.f,0.f,0.f}, a1 = {0.f,0.f,0.f,0.f};
        const u16* wrow = g_.Whh0 + (size_t)(j0 + col) * cD;
        const u16* xr0 = g_.z0p + (size_t)col * cD;
        const u16* xr1 = g_.z0p + (size_t)(16 + col) * cD;
        for (int kc = 0; kc < 8; ++kc){
          int k = kq * 256 + kc * 32 + kin;
          s16x8 bf = LD8(wrow + k);
          a0 = MFMA(LD8(xr0 + k), bf, a0);
          a1 = MFMA(LD8(xr1 + k), bf, a1);
        }
        #pragma unroll
        for (int r = 0; r < 4; ++r){
          lds.pc.acc[w][0][(l >> 4) * 4 + r][col] = a0[r];
          lds.pc.acc[w][1][(l >> 4) * 4 + r][col] = a1[r];
        }
        __syncthreads();
        #pragma unroll
        for (int it = 0; it < 2; ++it){
          int idx = it * 512 + tid;
          int b2 = idx >> 5, jj = idx & 31;
          int nt2 = jj >> 4, c2 = jj & 15;
          int mt = b2 >> 4, rr = b2 & 15;
          float v = 0.f;
          #pragma unroll
          for (int kq2 = 0; kq2 < 4; ++kq2) v += lds.pc.acc[nt2 * 4 + kq2][mt][rr][c2];
          int j = jb + jj;
          g_.g0buf[(size_t)(p ^ 1) * cB * 4096 + b2 * 4096 + j] =
              v + bf2f(g_.eyproj[(((size_t)s + 1) * cB + b2) * 4096 + j]);
        }
      }
    } else if (blk < 208){
      if (s < cNS - 1){
        // ---- q_next = z0' @ W_dec  (WdecT rows = a, K = D) ----
        const int jb = (blk - 192) * 32;
        const int nt = w >> 2, kq = w & 3;
        const int j0 = jb + nt * 16;
        f32x4 a0 = {0.f,0.f,0.f,0.f}, a1 = {0.f,0.f,0.f,0.f};
        const u16* wrow = g_.WdecT + (size_t)(j0 + col) * cD;
        const u16* xr0 = g_.z0p + (size_t)col * cD;
        const u16* xr1 = g_.z0p + (size_t)(16 + col) * cD;
        for (int kc = 0; kc < 8; ++kc){
          int k = kq * 256 + kc * 32 + kin;
          s16x8 bf = LD8(wrow + k);
          a0 = MFMA(LD8(xr0 + k), bf, a0);
          a1 = MFMA(LD8(xr1 + k), bf, a1);
        }
        #pragma unroll
        for (int r = 0; r < 4; ++r){
          lds.pc.acc[w][0][(l >> 4) * 4 + r][col] = a0[r];
          lds.pc.acc[w][1][(l >> 4) * 4 + r][col] = a1[r];
        }
        __syncthreads();
        #pragma unroll
        for (int it = 0; it < 2; ++it){
          int idx = it * 512 + tid;
          int b2 = idx >> 5, jj = idx & 31;
          int nt2 = jj >> 4, c2 = jj & 15;
          int mt = b2 >> 4, rr = b2 & 15;
          float v = 0.f;
          #pragma unroll
          for (int kq2 = 0; kq2 < 4; ++kq2) v += lds.pc.acc[nt2 * 4 + kq2][mt][rr][c2];
          g_.q[b2 * cA + jb + jj] = v;
        }
      }
    }
    gbar(g_.bar, bi++);
  }
}

// ------------------------------ epilogue -----------------------------------
// per (5-step group, 128-wide V chunk): logits tile + flash-style partials
__global__ __launch_bounds__(256) void k_ce1(const u16* __restrict__ z1all,
    const u16* __restrict__ Woutb, const float* __restrict__ bout,
    const int* __restrict__ ys, float* __restrict__ pmax, float* __restrict__ psum,
    int* __restrict__ pai, float* __restrict__ tgtl){
  int blk = blockIdx.x;
  int sc = blk / 40, vc = blk % 40;
  int tid = threadIdx.x, w = tid >> 6, l = tid & 63;
  int kin = 8 * (l >> 4), col = l & 15;
  int v0 = vc * 128 + w * 32;
  int vA = v0 + col, vB = v0 + 16 + col;
  float boA = (vA < cV) ? bout[vA] : 0.f;
  float boB = (vB < cV) ? bout[vB] : 0.f;
  const u16* wrA = Woutb + (size_t)((vA < cV) ? vA : cV - 1) * cD;
  const u16* wrB = Woutb + (size_t)((vB < cV) ? vB : cV - 1) * cD;
  __shared__ int tgt_sh[32];
  __shared__ float rsm[4][32], rss[4][32];
  __shared__ int rsi[4][32];
  for (int si = 0; si < 5; ++si){
    int s = sc * 5 + si;
    if (tid < 32) tgt_sh[tid] = (s < cL) ? ys[tid * cL + s] : EOS;
    __syncthreads();
    const u16* z1s = z1all + ((size_t)s + 1) * cB * cD;
    f32x4 aA0 = {0.f,0.f,0.f,0.f}, aA1 = {0.f,0.f,0.f,0.f};
    f32x4 aB0 = {0.f,0.f,0.f,0.f}, aB1 = {0.f,0.f,0.f,0.f};
    for (int kc = 0; kc < 32; ++kc){
      int k = kc * 32 + kin;
      s16x8 x0 = LD8(z1s + (size_t)col * cD + k);
      s16x8 x1 = LD8(z1s + (size_t)(16 + col) * cD + k);
      s16x8 bA = LD8(wrA + k);
      s16x8 bB = LD8(wrB + k);
      aA0 = MFMA(x0, bA, aA0); aA1 = MFMA(x1, bA, aA1);
      aB0 = MFMA(x0, bB, aB0); aB1 = MFMA(x1, bB, aB1);
    }
    #pragma unroll
    for (int mt = 0; mt < 2; ++mt)
    #pragma unroll
    for (int reg = 0; reg < 4; ++reg){
      int row = mt * 16 + (l >> 4) * 4 + reg;
      float va = (mt ? aA1[reg] : aA0[reg]) + boA; if (vA >= cV) va = -1e30f;
      float vb = (mt ? aB1[reg] : aB0[reg]) + boB; if (vB >= cV) vb = -1e30f;
      int tg = tgt_sh[row];
      if (vA == tg) tgtl[(size_t)s * cB + row] = va;
      if (vB == tg) tgtl[(size_t)s * cB + row] = vb;
      float mx = fmaxf(va, vb);
      int ix = (va >= vb) ? vA : vB;
      #pragma unroll
      for (int m = 1; m < 16; m <<= 1){
        float om = __shfl_xor(mx, m, 64);
        int oi = __shfl_xor(ix, m, 64);
        if (om > mx || (om == mx && oi < ix)){ mx = om; ix = oi; }
      }
      float se = __expf(va - mx) + __expf(vb - mx);
      #pragma unroll
      for (int m = 1; m < 16; m <<= 1) se += __shfl_xor(se, m, 64);
      if ((l & 15) == 0){ rsm[w][row] = mx; rss[w][row] = se; rsi[w][row] = ix; }
    }
    __syncthreads();
    if (tid < 32){
      int b = tid;
      float gm = -1e30f;
      #pragma unroll
      for (int w2 = 0; w2 < 4; ++w2) gm = fmaxf(gm, rsm[w2][b]);
      float gs = 0.f; float bv = -1e30f; int bix = 0x7fffffff;
      #pragma unroll
      for (int w2 = 0; w2 < 4; ++w2){
        gs += rss[w2][b] * __expf(rsm[w2][b] - gm);
        float v = rsm[w2][b]; int ii = rsi[w2][b];
        if (v > bv || (v == bv && ii < bix)){ bv = v; bix = ii; }
      }
      size_t o = ((size_t)s * cB + b) * 40 + vc;
      pmax[o] = gm; psum[o] = gs; pai[o] = bix;
    }
    __syncthreads();
  }
}

__global__ __launch_bounds__(64) void k_ce2(const float* __restrict__ pmax,
    const float* __restrict__ psum, const int* __restrict__ pai,
    const float* __restrict__ tgtl, const int* __restrict__ ys,
    float* __restrict__ cestep){
  int s = blockIdx.x, tid = threadIdx.x;
  float nll = 0.f, cor = 0.f;
  if (tid < 32){
    int b = tid;
    size_t o = ((size_t)s * cB + b) * 40;
    float gm = -1e30f;
    for (int c = 0; c < 40; ++c) gm = fmaxf(gm, pmax[o + c]);
    float gs = 0.f; float bv = -1e30f; int bix = 0x7fffffff;
    for (int c = 0; c < 40; ++c){
      gs += psum[o + c] * __expf(pmax[o + c] - gm);
      float v = pmax[o + c]; int ii = pai[o + c];
      if (v > bv || (v == bv && ii < bix)){ bv = v; bix = ii; }
    }
    nll = __logf(gs) + gm - tgtl[(size_t)s * cB + b];
    int tgt = (s < cL) ? ys[b * cL + s] : EOS;
    cor = (bix == tgt) ? 1.f : 0.f;
  }
  #pragma unroll
  for (int m = 1; m < 64; m <<= 1){
    nll += __shfl_xor(nll, m, 64); cor += __shfl_xor(cor, m, 64);
  }
  if (tid == 0){ cestep[s * 2] = nll; cestep[s * 2 + 1] = cor; }
}

__global__ __launch_bounds__(256) void k_ce3(const float* __restrict__ cestep,
                                             float* __restrict__ out){
  int tid = threadIdx.x;
  float nll = 0.f, cor = 0.f;
  for (int s = tid; s < cNS; s += 256){ nll += cestep[s * 2]; cor += cestep[s * 2 + 1]; }
  __shared__ float sn[4], sc_[4];
  int w = tid >> 6, l = tid & 63;
  #pragma unroll
  for (int m = 1; m < 64; m <<= 1){
    nll += __shfl_xor(nll, m, 64); cor += __shfl_xor(cor, m, 64);
  }
  if (l == 0){ sn[w] = nll; sc_[w] = cor; }
  __syncthreads();
  if (tid == 0){
    float a = sn[0] + sn[1] + sn[2] + sn[3];
    float b = sc_[0] + sc_[1] + sc_[2] + sc_[3];
    out[0] = a / (float)(cB * cNS) * (float)cL;   // nll.mean() * L
    out[1] = b / (float)(cB * cNS);               // accuracy
  }
}

// ------------------------------- host --------------------------------------
extern "C" void kernel_launch(void* const* d_in, const int* in_sizes, int n_in,
                              void* d_out, int out_size, void* d_ws, size_t ws_size,
                              hipStream_t stream){
  const float* hpad = (const float*)d_in[0];
  const int*   hlen = (const int*)d_in[1];
  const int*   ys   = (const int*)d_in[2];
  const float* embed= (const float*)d_in[3];
  const float* Wout = (const float*)d_in[4];
  const float* bout = (const float*)d_in[5];
  const float* Wenc = (const float*)d_in[6];
  const float* Wdec = (const float*)d_in[7];
  const float* vatt = (const float*)d_in[8];
  const float* Wih0 = (const float*)d_in[9];
  const float* bih0 = (const float*)d_in[10];
  const float* Whh0 = (const float*)d_in[11];
  const float* bhh0 = (const float*)d_in[12];
  const float* Wih1 = (const float*)d_in[13];
  const float* bih1 = (const float*)d_in[14];
  const float* Whh1 = (const float*)d_in[15];
  const float* bhh1 = (const float*)d_in[16];
  (void)in_sizes; (void)n_in; (void)out_size; (void)ws_size;

  char* base = (char*)d_ws;
  size_t off = 0;
  auto alloc = [&](size_t bytes) -> void* {
    void* r = base + off; off += (bytes + 255) & ~(size_t)255; return r;
  };
  // total ws usage ~166 MB
  int*   bar    = (int*)  alloc(2048 * sizeof(int));
  u16*   hpadM  = (u16*)  alloc((size_t)cB * cT * cE * 2);
  u16*   pe     = (u16*)  alloc((size_t)cB * cT * cA * 2);
  u16*   embb   = (u16*)  alloc((size_t)cV * cD * 2);
  u16*   eyproj = (u16*)  alloc((size_t)cNS * cB * 4096 * 2);
  u16*   z1all  = (u16*)  alloc((size_t)(cNS + 1) * cB * cD * 2);
  u16*   WencT  = (u16*)  alloc((size_t)cA * cE * 2);
  u16*   WdecT  = (u16*)  alloc((size_t)cA * cD * 2);
  u16*   Wih0m  = (u16*)  alloc((size_t)4096 * cD * 2);
  u16*   Waatt  = (u16*)  alloc((size_t)4096 * cE * 2);
  u16*   Whh0b  = (u16*)  alloc((size_t)4096 * cD * 2);
  u16*   Wih1b  = (u16*)  alloc((size_t)4096 * cD * 2);
  u16*   Whh1b  = (u16*)  alloc((size_t)4096 * cD * 2);
  u16*   Woutb  = (u16*)  alloc((size_t)cV * cD * 2);
  float* bias01 = (float*)alloc(4096 * 4);
  float* qbuf   = (float*)alloc((size_t)cB * cA * 4);
  float* stats  = (float*)alloc((size_t)cB * 8 * 2 * 4);
  u16*   acpart = (u16*)  alloc((size_t)cB * 8 * cE * 2);
  float* g0buf  = (float*)alloc((size_t)2 * cB * 4096 * 4);
  float* hh1buf = (float*)alloc((size_t)cB * 4096 * 4);
  u16*   z0p    = (u16*)  alloc((size_t)cB * cD * 2);
  float* c0     = (float*)alloc((size_t)2 * cB * cD * 4);
  float* c1     = (float*)alloc((size_t)2 * cB * cD * 4);
  float* pmax   = (float*)alloc((size_t)cNS * cB * 40 * 4);
  float* psum   = (float*)alloc((size_t)cNS * cB * 40 * 4);
  int*   pai    = (int*)  alloc((size_t)cNS * cB * 40 * 4);
  float* tgtl   = (float*)alloc((size_t)cNS * cB * 4);
  float* cestep = (float*)alloc((size_t)cNS * 2 * 4);

  k_init<<<64, 256, 0, stream>>>(bar, qbuf, c0, c1, z1all);
  k_cvt<<<2048, 256, 0, stream>>>(hpad, hpadM, cB * cT * cE / 4);
  k_cvt<<<2048, 256, 0, stream>>>(embed, embb, cV * cD / 4);
  k_cvt<<<1024, 256, 0, stream>>>(Whh0, Whh0b, 4096 * cD / 4);
  k_cvt<<<1024, 256, 0, stream>>>(Wih1, Wih1b, 4096 * cD / 4);
  k_cvt<<<1024, 256, 0, stream>>>(Whh1, Whh1b, 4096 * cD / 4);
  k_cvt<<<2048, 256, 0, stream>>>(Wout, Woutb, cV * cD / 4);
  k_slice<<<1024, 256, 0, stream>>>(Wih0, Wih0m, 4096 * cD, 10, 1536, 0);
  k_slice<<<512, 256, 0, stream>>>(Wih0, Waatt, 4096 * cE, 9, 1536, 1024);
  k_transp<<<256, 256, 0, stream>>>(Wenc, WencT, cA * cE, 9, cA);
  k_transp<<<512, 256, 0, stream>>>(Wdec, WdecT, cA * cD, 10, cA);
  k_bias<<<16, 256, 0, stream>>>(bih1, bhh1, bias01, 4096);
  k_pe<<<400, 256, 0, stream>>>(hpadM, WencT, pe);
  k_eyproj<<<75, 256, 0, stream>>>(embb, ys, Wih0m, bih0, bhh0, eyproj, g0buf);

  LoopArgs la;
  la.hlen = hlen; la.pe = pe; la.hpadM = hpadM; la.eyproj = eyproj;
  la.WdecT = WdecT; la.Waatt = Waatt; la.Whh0 = Whh0b; la.Wih1 = Wih1b;
  la.Whh1 = Whh1b; la.vatt = vatt; la.bias01 = bias01;
  la.q = qbuf; la.stats = stats; la.acpart = acpart; la.g0buf = g0buf;
  la.hh1buf = hh1buf; la.z0p = z0p; la.c0 = c0; la.c1 = c1; la.z1all = z1all;
  la.bar = bar;
  k_loop<<<NBLK, 512, 0, stream>>>(la);

  k_ce1<<<1200, 256, 0, stream>>>(z1all, Woutb, bout, ys, pmax, psum, pai, tgtl);
  k_ce2<<<cNS, 64, 0, stream>>>(pmax, psum, pai, tgtl, ys, cestep);
  k_ce3<<<1, 256, 0, stream>>>(cestep, (float*)d_out);
}

// Round 2
// 13310.393 us; speedup vs baseline: 1.3289x; 1.3289x over previous
//
#include <hip/hip_runtime.h>

// ---------------------------------------------------------------------------
// Decoder_60868276519063: attention-LSTM decoder forward (loss, acc)
// B=32 T=800 E=512 D=1024 V=5000 L=149 (150 steps) A=512
// Round 2: fused fp8 attention (no-max softmax), store-only grid barrier,
// LDS-staged MFMA GEMVs, 4 phases/step.
// ---------------------------------------------------------------------------

typedef unsigned short u16;
typedef unsigned char u8;
typedef float f32x4 __attribute__((ext_vector_type(4)));
typedef float f32x2 __attribute__((ext_vector_type(2)));
typedef short s16x8 __attribute__((ext_vector_type(8)));

constexpr int cB = 32, cT = 800, cE = 512, cD = 1024, cV = 5000, cL = 149,
              cNS = 150, cA = 512;
constexpr int SOS = 1, EOS = 2;
constexpr int NBLK = 256;   // persistent grid, 1 block/CU

__device__ __forceinline__ float bf2f(u16 x){
  union { unsigned u; float f; } v; v.u = ((unsigned)x) << 16; return v.f;
}
__device__ __forceinline__ u16 f2bf(float f){
  union { float f; unsigned u; } v; v.f = f;
  unsigned r = v.u + 0x7FFFu + ((v.u >> 16) & 1u);
  return (u16)(r >> 16);
}
__device__ __forceinline__ float frcp(float x){ return __builtin_amdgcn_rcpf(x); }
__device__ __forceinline__ float fsigm(float x){ return frcp(1.f + __expf(-x)); }
__device__ __forceinline__ float ftanh(float x){
  float u = __expf(2.f * x);
  return 1.f - 2.f * frcp(u + 1.f);   // x>>0: u=inf -> 1 ; x<<0: u~0 -> -1
}
__device__ __forceinline__ f32x4 MFMA(s16x8 a, s16x8 b, f32x4 c){
  return __builtin_amdgcn_mfma_f32_16x16x32_bf16(a, b, c, 0, 0, 0);
}
__device__ __forceinline__ s16x8 LD8(const u16* p){ return *(const s16x8*)p; }
__device__ __forceinline__ u8 f2fp8(float x){
  return (u8)(__builtin_amdgcn_cvt_pk_fp8_f32(x, x, 0, false) & 0xFF);
}
__device__ __forceinline__ void unpack8(unsigned lo, unsigned hi, float* o){
  f32x2 a = __builtin_amdgcn_cvt_pk_f32_fp8((int)lo, false);
  f32x2 b = __builtin_amdgcn_cvt_pk_f32_fp8((int)lo, true);
  f32x2 c = __builtin_amdgcn_cvt_pk_f32_fp8((int)hi, false);
  f32x2 d = __builtin_amdgcn_cvt_pk_f32_fp8((int)hi, true);
  o[0]=a[0]; o[1]=a[1]; o[2]=b[0]; o[3]=b[1];
  o[4]=c[0]; o[5]=c[1]; o[6]=d[0]; o[7]=d[1];
}

// ------------------------------- prologue ----------------------------------
__global__ void k_init(int* bar, float* q, float* c0, float* c1, u16* z1slot0){
  int i = blockIdx.x * blockDim.x + threadIdx.x, n = gridDim.x * blockDim.x;
  for (int k = i; k < 512; k += n) bar[k] = 0;
  for (int k = i; k < cB * cA; k += n) q[k] = 0.f;
  for (int k = i; k < 2 * cB * cD; k += n){ c0[k] = 0.f; c1[k] = 0.f; }
  for (int k = i; k < cB * cD; k += n) z1slot0[k] = 0;
}

__global__ void k_cvt(const float* __restrict__ s, u16* __restrict__ d, int n4){
  int i = blockIdx.x * blockDim.x + threadIdx.x, st = gridDim.x * blockDim.x;
  for (int k = i; k < n4; k += st){
    float4 v = ((const float4*)s)[k];
    ushort4 o; o.x = f2bf(v.x); o.y = f2bf(v.y); o.z = f2bf(v.z); o.w = f2bf(v.w);
    ((ushort4*)d)[k] = o;
  }
}

// interleaved fp8 pack of hpad into ph8: per (row,grp of 8 cols):
// bytes [grp*16 .. grp*16+7] = pe (written by k_pe), [+8 .. +15] = hpad
__global__ void k_cvt8I(const float* __restrict__ s, u8* __restrict__ d, int n){
  int i = blockIdx.x * blockDim.x + threadIdx.x, st = gridDim.x * blockDim.x;
  for (int k = i; k < n; k += st){
    int row = k >> 6, grp = k & 63;
    const float4* p = (const float4*)(s + (size_t)row * 512 + grp * 8);
    float4 v0 = p[0], v1 = p[1];
    unsigned lo = (unsigned)__builtin_amdgcn_cvt_pk_fp8_f32(v0.x, v0.y, 0, false);
    lo = (unsigned)__builtin_amdgcn_cvt_pk_fp8_f32(v0.z, v0.w, (int)lo, true);
    unsigned hi = (unsigned)__builtin_amdgcn_cvt_pk_fp8_f32(v1.x, v1.y, 0, false);
    hi = (unsigned)__builtin_amdgcn_cvt_pk_fp8_f32(v1.z, v1.w, (int)hi, true);
    *(uint2*)(d + (size_t)row * 1024 + grp * 16 + 8) = make_uint2(lo, hi);
  }
}

// dst[r][c] = src[r][coff+c], cols = 1<<cshift
__global__ void k_slice(const float* __restrict__ s, u16* __restrict__ d, int n,
                        int cshift, int srcld, int coff){
  int i = blockIdx.x * blockDim.x + threadIdx.x, st = gridDim.x * blockDim.x;
  int cmask = (1 << cshift) - 1;
  for (int k = i; k < n; k += st){
    int r = k >> cshift, c = k & cmask;
    d[k] = f2bf(s[(size_t)r * srcld + coff + c]);
  }
}

// row-permuted bf16 convert: dst row jj = blkk*64+g*16+c <-> orig g*1024+blkk*16+c
__global__ void k_permW(const float* __restrict__ s, u16* __restrict__ d, int n,
                        int kshift, int srcld, int coff){
  int i = blockIdx.x * blockDim.x + threadIdx.x, st = gridDim.x * blockDim.x;
  int kmask = (1 << kshift) - 1;
  for (int k = i; k < n; k += st){
    int jj = k >> kshift, kk = k & kmask;
    int blkk = jj >> 6, rem = jj & 63, g = rem >> 4, c = rem & 15;
    int orig = g * 1024 + blkk * 16 + c;
    d[k] = f2bf(s[(size_t)orig * srcld + coff + kk]);
  }
}

// dst[a][dd] = src[dd][a], cols_out = 1<<rshift
__global__ void k_transp(const float* __restrict__ s, u16* __restrict__ d, int n,
                         int rshift, int csrc){
  int i = blockIdx.x * blockDim.x + threadIdx.x, st = gridDim.x * blockDim.x;
  int mask = (1 << rshift) - 1;
  for (int k = i; k < n; k += st){
    int dd = k & mask, a = k >> rshift;
    d[k] = f2bf(s[(size_t)dd * csrc + a]);
  }
}

__global__ void k_bias(const float* a, const float* b, float* o, int n){
  int i = blockIdx.x * blockDim.x + threadIdx.x, st = gridDim.x * blockDim.x;
  for (int k = i; k < n; k += st) o[k] = a[k] + b[k];
}

// pe -> fp8 interleaved into ph8 (bytes [grp*16 .. +7])
__global__ __launch_bounds__(256) void k_pe(const u16* __restrict__ hpadM,
                                            const u16* __restrict__ WencT,
                                            u8* __restrict__ ph8){
  int tid = threadIdx.x, w = tid >> 6, l = tid & 63;
  int mt = blockIdx.x * 4 + w;           // 1600 mtiles of 16 rows
  int m0 = mt * 16;
  int kin = 8 * (l >> 4), col = l & 15;
  const u16* xrow = hpadM + (size_t)(m0 + col) * cE;
  for (int ng = 0; ng < 4; ++ng){
    f32x4 acc[8] = {};
    for (int kc = 0; kc < 16; ++kc){
      int k = kc * 32 + kin;
      s16x8 a = LD8(xrow + k);
      #pragma unroll
      for (int nt = 0; nt < 8; ++nt){
        const u16* wr = WencT + (size_t)((ng * 8 + nt) * 16 + col) * cE + k;
        acc[nt] = MFMA(a, LD8(wr), acc[nt]);
      }
    }
    #pragma unroll
    for (int nt = 0; nt < 8; ++nt){
      int a0 = (ng * 8 + nt) * 16 + col;
      #pragma unroll
      for (int r = 0; r < 4; ++r){
        int row = m0 + (l >> 4) * 4 + r;
        ph8[(size_t)row * 1024 + ((a0 >> 3) << 4) + (a0 & 7)] = f2fp8(acc[nt][r]);
      }
    }
  }
}

// eyproj[s*32+b][j] = embed[ys_in] @ W_ih0[:, :1024]^T + b_ih0 + b_hh0
// also writes g0buf parity0 for step 0 (hh0(0) = 0)
__global__ __launch_bounds__(256) void k_eyproj(const u16* __restrict__ embb,
    const int* __restrict__ ys, const u16* __restrict__ Wih0m,
    const float* __restrict__ bih0, const float* __restrict__ bhh0,
    u16* __restrict__ eyproj, float* __restrict__ g0buf){
  int tid = threadIdx.x, w = tid >> 6, l = tid & 63;
  int mt = blockIdx.x * 4 + w;           // 300 mtiles
  int m0 = mt * 16;
  int kin = 8 * (l >> 4), col = l & 15;
  int r = m0 + col;
  int s = r >> 5, b = r & 31;
  int tok = (s == 0) ? SOS : ys[b * cL + (s - 1)];
  const u16* xrow = embb + (size_t)tok * cD;
  for (int ng = 0; ng < 32; ++ng){
    f32x4 acc[8] = {};
    for (int kc = 0; kc < 32; ++kc){
      int k = kc * 32 + kin;
      s16x8 a = LD8(xrow + k);
      #pragma unroll
      for (int nt = 0; nt < 8; ++nt){
        const u16* wr = Wih0m + (size_t)((ng * 8 + nt) * 16 + col) * cD + k;
        acc[nt] = MFMA(a, LD8(wr), acc[nt]);
      }
    }
    #pragma unroll
    for (int nt = 0; nt < 8; ++nt){
      int j = (ng * 8 + nt) * 16 + col;
      float bj = bih0[j] + bhh0[j];
      #pragma unroll
      for (int rr = 0; rr < 4; ++rr){
        int row = m0 + (l >> 4) * 4 + rr;
        float val = acc[nt][rr] + bj;
        eyproj[(size_t)row * 4096 + j] = f2bf(val);
        if (row < 32) g0buf[row * 4096 + j] = val;   // s==0 rows
      }
    }
  }
}

// ------------------------------ main loop ----------------------------------
struct LoopArgs {
  const int* hlen;
  const u8* ph8;                 // [B*T][1024] bytes: [8 pe fp8 | 8 hpad fp8] x64
  const u16* eyproj; const u16* Wap; const u16* Whh1; const u16* Wcat;
  const float* vatt; const float* bias01;
  float* q; float* accbuf; float* lpart; u16* att_bf;
  float* g0buf; float* hh1buf; u16* z0bf;
  float* c0; float* c1; u16* z1all;
  int* bar;
};

struct P1Lds { float red[8][512]; float ls[8]; };
struct GvLds { u16 x[16 * 1032]; float acc[8][2][16][16]; };
union LoopLds { P1Lds p1; GvLds gv; };   // 49.4 KB

// store-only flag barrier: flags[0..255], release words at 256 + g*16
__device__ __forceinline__ void gbar(int* bar, int blk, int target){
  __syncthreads();
  if (threadIdx.x == 0){
    __threadfence();
    __hip_atomic_store(&bar[blk], target, __ATOMIC_RELAXED, __HIP_MEMORY_SCOPE_AGENT);
  }
  if (blk == NBLK - 1){          // collector = block 255 (idle in P2..P4)
    if (threadIdx.x < NBLK){
      while (__hip_atomic_load(&bar[threadIdx.x], __ATOMIC_RELAXED,
                               __HIP_MEMORY_SCOPE_AGENT) < target)
        __builtin_amdgcn_s_sleep(1);
    }
    __syncthreads();
    if (threadIdx.x < 8){
      __threadfence();
      __hip_atomic_store(&bar[256 + threadIdx.x * 16], target, __ATOMIC_RELAXED,
                         __HIP_MEMORY_SCOPE_AGENT);
    }
  }
  if (threadIdx.x == 0){
    int* rel = &bar[256 + (blk >> 5) * 16];
    while (__hip_atomic_load(rel, __ATOMIC_RELAXED,
                             __HIP_MEMORY_SCOPE_AGENT) < target)
      __builtin_amdgcn_s_sleep(1);
    __threadfence();
  }
  __syncthreads();
}

// block GEMV: out[32][64] = x[32][K] @ W[jb..jb+63][K]^T via MFMA.
// x staged in LDS (two 16-row passes, +8 u16 pad -> even ds_read_b128 banks),
// weight slice kept in registers across both passes. Result in L.gv.acc:
// acc[nt*2+kh][mt][row16][col], out(b,jj) = sum over kh.
template<int K>
__device__ __forceinline__ void gemv_block(const u16* __restrict__ xg,
    const u16* __restrict__ wb, LoopLds& L, int tid){
  constexpr int SP = K + 8;
  const int w = tid >> 6, l = tid & 63;
  const int col = l & 15, kin = 8 * (l >> 4);
  const int nt = w >> 1, kh = w & 1;
  const u16* wr = wb + (size_t)(nt * 16 + col) * K + kh * (K / 2) + kin;
  const int sr = tid >> 5, sc = tid & 31;
  f32x4 a0 = {0.f,0.f,0.f,0.f}, a1 = {0.f,0.f,0.f,0.f};
  s16x8 bfr[K / 64];
  #pragma unroll
  for (int kk = 0; kk < K / 256; ++kk){          // stage rows 0..15
    int c = sc * 8 + kk * 256;
    *(s16x8*)&L.gv.x[sr * SP + c] = LD8(xg + (size_t)sr * K + c);
  }
  __syncthreads();
  #pragma unroll
  for (int kc = 0; kc < K / 64; ++kc){
    bfr[kc] = LD8(wr + kc * 32);
    a0 = MFMA(*(const s16x8*)&L.gv.x[col * SP + kh * (K / 2) + kc * 32 + kin],
              bfr[kc], a0);
  }
  __syncthreads();
  #pragma unroll
  for (int kk = 0; kk < K / 256; ++kk){          // stage rows 16..31
    int c = sc * 8 + kk * 256;
    *(s16x8*)&L.gv.x[sr * SP + c] = LD8(xg + (size_t)(16 + sr) * K + c);
  }
  __syncthreads();
  #pragma unroll
  for (int kc = 0; kc < K / 64; ++kc)
    a1 = MFMA(*(const s16x8*)&L.gv.x[col * SP + kh * (K / 2) + kc * 32 + kin],
              bfr[kc], a1);
  const int hi4 = (l >> 4) * 4;
  #pragma unroll
  for (int r = 0; r < 4; ++r){
    L.gv.acc[w][0][hi4 + r][col] = a0[r];
    L.gv.acc[w][1][hi4 + r][col] = a1[r];
  }
  __syncthreads();
}

__global__ __launch_bounds__(512, 2) void k_loop(LoopArgs g_){
  __shared__ LoopLds L;
  const int blk = blockIdx.x, tid = threadIdx.x;
  const int w = tid >> 6, l = tid & 63;
  float vv[8];
  #pragma unroll
  for (int i = 0; i < 8; ++i) vv[i] = g_.vatt[l * 8 + i];
  const int b_att = blk >> 3, oct = blk & 7;
  const int hl = g_.hlen[b_att];
  const int t0 = oct * 100;
  const int t1 = (t0 + 100 < hl) ? t0 + 100 : hl;
  const size_t rowb = ((size_t)b_att * cT) * 1024 + (size_t)l * 16;
  int target = 0;
  for (int s = 0; s < cNS; ++s){
    const int p = s & 1;
    // ============ P1: fused attention partials (no-max softmax) ===========
    {
      float qv[8];
      const float* qb = g_.q + b_att * cA + l * 8;
      #pragma unroll
      for (int i = 0; i < 8; ++i) qv[i] = qb[i];
      float acc[8] = {0.f,0.f,0.f,0.f,0.f,0.f,0.f,0.f};
      float lsum = 0.f;
      #pragma unroll 2
      for (int t = t0 + w; t < t1; t += 8){
        uint4 v = *(const uint4*)(g_.ph8 + rowb + (size_t)t * 1024);
        float x[8]; unpack8(v.x, v.y, x);
        float e_ = 0.f;
        #pragma unroll
        for (int i = 0; i < 8; ++i) e_ += vv[i] * ftanh(x[i] + qv[i]);
        #pragma unroll
        for (int m = 1; m < 64; m <<= 1) e_ += __shfl_xor(e_, m, 64);
        float wt = __expf(e_);        // |e| <= sum|v_att| ~ 8.2, safe
        lsum += wt;
        float h[8]; unpack8(v.z, v.w, h);
        #pragma unroll
        for (int i = 0; i < 8; ++i) acc[i] = fmaf(wt, h[i], acc[i]);
      }
      f32x4 lo = {acc[0], acc[1], acc[2], acc[3]};
      f32x4 hi = {acc[4], acc[5], acc[6], acc[7]};
      *(f32x4*)&L.p1.red[w][l * 8] = lo;
      *(f32x4*)&L.p1.red[w][l * 8 + 4] = hi;
      if (l == 0) L.p1.ls[w] = lsum;
      __syncthreads();
      float vsum = 0.f;
      #pragma unroll
      for (int ww = 0; ww < 8; ++ww) vsum += L.p1.red[ww][tid];
      g_.accbuf[((size_t)b_att * 8 + oct) * 512 + tid] = vsum;
      if (tid == 0){
        float ls = 0.f;
        #pragma unroll
        for (int ww = 0; ww < 8; ++ww) ls += L.p1.ls[ww];
        g_.lpart[b_att * 8 + oct] = ls;
      }
    }
    gbar(g_.bar, blk, ++target);
    // ============ P2: combine att_c (32 blk) + hh1 GEMV (64 blk) ==========
    if (blk < 32){
      const int b = blk;
      float lt = 0.f;
      #pragma unroll
      for (int o = 0; o < 8; ++o) lt += g_.lpart[b * 8 + o];
      float inv = 1.f / lt;
      float sv = 0.f;
      #pragma unroll
      for (int o = 0; o < 8; ++o) sv += g_.accbuf[((size_t)b * 8 + o) * 512 + tid];
      g_.att_bf[b * 512 + tid] = f2bf(sv * inv);
    } else if (blk >= 64 && blk < 128){
      const int jb = (blk - 64) * 64;
      gemv_block<1024>(g_.z1all + (size_t)s * cB * cD,
                       g_.Whh1 + (size_t)jb * 1024, L, tid);
      #pragma unroll
      for (int it = 0; it < 4; ++it){
        int idx = it * 512 + tid;
        int b2 = idx >> 6, jj = idx & 63;
        int nt2 = jj >> 4, c2 = jj & 15, mt = b2 >> 4, rr = b2 & 15;
        float v = L.gv.acc[nt2*2][mt][rr][c2] + L.gv.acc[nt2*2+1][mt][rr][c2];
        g_.hh1buf[b2 * 4096 + jb + jj] = v + g_.bias01[jb + jj];
      }
    }
    gbar(g_.bar, blk, ++target);
    // ============ P3: Wa GEMV + LSTM0 (64 blk) ============================
    if (blk < 64){
      gemv_block<512>(g_.att_bf, g_.Wap + (size_t)blk * 64 * 512, L, tid);
      int b2 = tid >> 4, dc = tid & 15;
      int d = blk * 16 + dc;
      int mt = b2 >> 4, rr = b2 & 15;
      float gate[4];
      #pragma unroll
      for (int g = 0; g < 4; ++g){
        gate[g] = L.gv.acc[g*2][mt][rr][dc] + L.gv.acc[g*2+1][mt][rr][dc] +
                  g_.g0buf[(size_t)p * cB * 4096 + b2 * 4096 + g * 1024 + d];
      }
      float c = fsigm(gate[1]) * g_.c0[(size_t)p * cB * cD + b2 * cD + d] +
                fsigm(gate[0]) * ftanh(gate[2]);
      float z = fsigm(gate[3]) * ftanh(c);
      g_.c0[(size_t)(p ^ 1) * cB * cD + b2 * cD + d] = c;
      g_.z0bf[b2 * cD + d] = f2bf(z);
    }
    gbar(g_.bar, blk, ++target);
    // ============ P4: Wcat GEMVs (136 blk) ================================
    if (blk < 136){
      gemv_block<1024>(g_.z0bf, g_.Wcat + (size_t)blk * 64 * 1024, L, tid);
      if (blk < 64){
        // Wih1' section -> LSTM1
        int b2 = tid >> 4, dc = tid & 15;
        int d = blk * 16 + dc;
        int mt = b2 >> 4, rr = b2 & 15;
        float gate[4];
        #pragma unroll
        for (int g = 0; g < 4; ++g){
          gate[g] = L.gv.acc[g*2][mt][rr][dc] + L.gv.acc[g*2+1][mt][rr][dc] +
                    g_.hh1buf[b2 * 4096 + g * 1024 + d];
        }
        float c = fsigm(gate[1]) * g_.c1[(size_t)p * cB * cD + b2 * cD + d] +
                  fsigm(gate[0]) * ftanh(gate[2]);
        float z = fsigm(gate[3]) * ftanh(c);
        g_.c1[(size_t)(p ^ 1) * cB * cD + b2 * cD + d] = c;
        g_.z1all[((size_t)s + 1) * cB * cD + b2 * cD + d] = f2bf(z);
      } else if (blk < 128){
        // Whh0 section -> g0buf[p^1] = hh0 + eyproj[s+1]
        if (s < cNS - 1){
          const int jb = (blk - 64) * 64;
          #pragma unroll
          for (int it = 0; it < 4; ++it){
            int idx = it * 512 + tid;
            int b2 = idx >> 6, jj = idx & 63;
            int nt2 = jj >> 4, c2 = jj & 15, mt = b2 >> 4, rr = b2 & 15;
            float v = L.gv.acc[nt2*2][mt][rr][c2] + L.gv.acc[nt2*2+1][mt][rr][c2];
            g_.g0buf[(size_t)(p ^ 1) * cB * 4096 + b2 * 4096 + jb + jj] =
                v + bf2f(g_.eyproj[(((size_t)s + 1) * cB + b2) * 4096 + jb + jj]);
          }
        }
      } else {
        // WdecT section -> q_next
        const int jb = (blk - 128) * 64;
        #pragma unroll
        for (int it = 0; it < 4; ++it){
          int idx = it * 512 + tid;
          int b2 = idx >> 6, jj = idx & 63;
          int nt2 = jj >> 4, c2 = jj & 15, mt = b2 >> 4, rr = b2 & 15;
          float v = L.gv.acc[nt2*2][mt][rr][c2] + L.gv.acc[nt2*2+1][mt][rr][c2];
          g_.q[b2 * cA + jb + jj] = v;
        }
      }
    }
    gbar(g_.bar, blk, ++target);
  }
}

// ------------------------------ epilogue -----------------------------------
__global__ __launch_bounds__(256) void k_ce1(const u16* __restrict__ z1all,
    const u16* __restrict__ Woutb, const float* __restrict__ bout,
    const int* __restrict__ ys, float* __restrict__ pmax, float* __restrict__ psum,
    int* __restrict__ pai, float* __restrict__ tgtl){
  int blk = blockIdx.x;
  int sc = blk / 40, vc = blk % 40;
  int tid = threadIdx.x, w = tid >> 6, l = tid & 63;
  int kin = 8 * (l >> 4), col = l & 15;
  int v0 = vc * 128 + w * 32;
  int vA = v0 + col, vB = v0 + 16 + col;
  float boA = (vA < cV) ? bout[vA] : 0.f;
  float boB = (vB < cV) ? bout[vB] : 0.f;
  const u16* wrA = Woutb + (size_t)((vA < cV) ? vA : cV - 1) * cD;
  const u16* wrB = Woutb + (size_t)((vB < cV) ? vB : cV - 1) * cD;
  __shared__ int tgt_sh[32];
  __shared__ float rsm[4][32], rss[4][32];
  __shared__ int rsi[4][32];
  for (int si = 0; si < 5; ++si){
    int s = sc * 5 + si;
    if (tid < 32) tgt_sh[tid] = (s < cL) ? ys[tid * cL + s] : EOS;
    __syncthreads();
    const u16* z1s = z1all + ((size_t)s + 1) * cB * cD;
    f32x4 aA0 = {0.f,0.f,0.f,0.f}, aA1 = {0.f,0.f,0.f,0.f};
    f32x4 aB0 = {0.f,0.f,0.f,0.f}, aB1 = {0.f,0.f,0.f,0.f};
    for (int kc = 0; kc < 32; ++kc){
      int k = kc * 32 + kin;
      s16x8 x0 = LD8(z1s + (size_t)col * cD + k);
      s16x8 x1 = LD8(z1s + (size_t)(16 + col) * cD + k);
      s16x8 bA = LD8(wrA + k);
      s16x8 bB = LD8(wrB + k);
      aA0 = MFMA(x0, bA, aA0); aA1 = MFMA(x1, bA, aA1);
      aB0 = MFMA(x0, bB, aB0); aB1 = MFMA(x1, bB, aB1);
    }
    #pragma unroll
    for (int mt = 0; mt < 2; ++mt)
    #pragma unroll
    for (int reg = 0; reg < 4; ++reg){
      int row = mt * 16 + (l >> 4) * 4 + reg;
      float va = (mt ? aA1[reg] : aA0[reg]) + boA; if (vA >= cV) va = -1e30f;
      float vb = (mt ? aB1[reg] : aB0[reg]) + boB; if (vB >= cV) vb = -1e30f;
      int tg = tgt_sh[row];
      if (vA == tg) tgtl[(size_t)s * cB + row] = va;
      if (vB == tg) tgtl[(size_t)s * cB + row] = vb;
      float mx = fmaxf(va, vb);
      int ix = (va >= vb) ? vA : vB;
      #pragma unroll
      for (int m = 1; m < 16; m <<= 1){
        float om = __shfl_xor(mx, m, 64);
        int oi = __shfl_xor(ix, m, 64);
        if (om > mx || (om == mx && oi < ix)){ mx = om; ix = oi; }
      }
      float se = __expf(va - mx) + __expf(vb - mx);
      #pragma unroll
      for (int m = 1; m < 16; m <<= 1) se += __shfl_xor(se, m, 64);
      if ((l & 15) == 0){ rsm[w][row] = mx; rss[w][row] = se; rsi[w][row] = ix; }
    }
    __syncthreads();
    if (tid < 32){
      int b = tid;
      float gm = -1e30f;
      #pragma unroll
      for (int w2 = 0; w2 < 4; ++w2) gm = fmaxf(gm, rsm[w2][b]);
      float gs = 0.f; float bv = -1e30f; int bix = 0x7fffffff;
      #pragma unroll
      for (int w2 = 0; w2 < 4; ++w2){
        gs += rss[w2][b] * __expf(rsm[w2][b] - gm);
        float v = rsm[w2][b]; int ii = rsi[w2][b];
        if (v > bv || (v == bv && ii < bix)){ bv = v; bix = ii; }
      }
      size_t o = ((size_t)s * cB + b) * 40 + vc;
      pmax[o] = gm; psum[o] = gs; pai[o] = bix;
    }
    __syncthreads();
  }
}

__global__ __launch_bounds__(64) void k_ce2(const float* __restrict__ pmax,
    const float* __restrict__ psum, const int* __restrict__ pai,
    const float* __restrict__ tgtl, const int* __restrict__ ys,
    float* __restrict__ cestep){
  int s = blockIdx.x, tid = threadIdx.x;
  float nll = 0.f, cor = 0.f;
  if (tid < 32){
    int b = tid;
    size_t o = ((size_t)s * cB + b) * 40;
    float gm = -1e30f;
    for (int c = 0; c < 40; ++c) gm = fmaxf(gm, pmax[o + c]);
    float gs = 0.f; float bv = -1e30f; int bix = 0x7fffffff;
    for (int c = 0; c < 40; ++c){
      gs += psum[o + c] * __expf(pmax[o + c] - gm);
      float v = pmax[o + c]; int ii = pai[o + c];
      if (v > bv || (v == bv && ii < bix)){ bv = v; bix = ii; }
    }
    nll = __logf(gs) + gm - tgtl[(size_t)s * cB + b];
    int tgt = (s < cL) ? ys[b * cL + s] : EOS;
    cor = (bix == tgt) ? 1.f : 0.f;
  }
  #pragma unroll
  for (int m = 1; m < 64; m <<= 1){
    nll += __shfl_xor(nll, m, 64); cor += __shfl_xor(cor, m, 64);
  }
  if (tid == 0){ cestep[s * 2] = nll; cestep[s * 2 + 1] = cor; }
}

__global__ __launch_bounds__(256) void k_ce3(const float* __restrict__ cestep,
                                             float* __restrict__ out){
  int tid = threadIdx.x;
  float nll = 0.f, cor = 0.f;
  for (int s = tid; s < cNS; s += 256){ nll += cestep[s * 2]; cor += cestep[s * 2 + 1]; }
  __shared__ float sn[4], sc_[4];
  int w = tid >> 6, l = tid & 63;
  #pragma unroll
  for (int m = 1; m < 64; m <<= 1){
    nll += __shfl_xor(nll, m, 64); cor += __shfl_xor(cor, m, 64);
  }
  if (l == 0){ sn[w] = nll; sc_[w] = cor; }
  __syncthreads();
  if (tid == 0){
    float a = sn[0] + sn[1] + sn[2] + sn[3];
    float b = sc_[0] + sc_[1] + sc_[2] + sc_[3];
    out[0] = a / (float)(cB * cNS) * (float)cL;   // nll.mean() * L
    out[1] = b / (float)(cB * cNS);               // accuracy
  }
}

// ------------------------------- host --------------------------------------
extern "C" void kernel_launch(void* const* d_in, const int* in_sizes, int n_in,
                              void* d_out, int out_size, void* d_ws, size_t ws_size,
                              hipStream_t stream){
  const float* hpad = (const float*)d_in[0];
  const int*   hlen = (const int*)d_in[1];
  const int*   ys   = (const int*)d_in[2];
  const float* embed= (const float*)d_in[3];
  const float* Wout = (const float*)d_in[4];
  const float* bout = (const float*)d_in[5];
  const float* Wenc = (const float*)d_in[6];
  const float* Wdec = (const float*)d_in[7];
  const float* vatt = (const float*)d_in[8];
  const float* Wih0 = (const float*)d_in[9];
  const float* bih0 = (const float*)d_in[10];
  const float* Whh0 = (const float*)d_in[11];
  const float* bhh0 = (const float*)d_in[12];
  const float* Wih1 = (const float*)d_in[13];
  const float* bih1 = (const float*)d_in[14];
  const float* Whh1 = (const float*)d_in[15];
  const float* bhh1 = (const float*)d_in[16];
  (void)in_sizes; (void)n_in; (void)out_size; (void)ws_size;

  char* base = (char*)d_ws;
  size_t off = 0;
  auto alloc = [&](size_t bytes) -> void* {
    void* r = base + off; off += (bytes + 255) & ~(size_t)255; return r;
  };
  int*   bar    = (int*)  alloc(512 * sizeof(int));
  u16*   hpadM  = (u16*)  alloc((size_t)cB * cT * cE * 2);        // 26.2MB
  u8*    ph8    = (u8*)   alloc((size_t)cB * cT * 1024);          // 26.2MB
  u16*   embb   = (u16*)  alloc((size_t)cV * cD * 2);             // 10.2MB
  u16*   eyproj = (u16*)  alloc((size_t)cNS * cB * 4096 * 2);     // 39.3MB
  u16*   z1all  = (u16*)  alloc((size_t)(cNS + 1) * cB * cD * 2); // 9.9MB
  u16*   WencT  = (u16*)  alloc((size_t)cA * cE * 2);
  u16*   Wih0m  = (u16*)  alloc((size_t)4096 * cD * 2);           // 8.4MB
  u16*   Wap    = (u16*)  alloc((size_t)4096 * cE * 2);           // 4.2MB
  u16*   Whh1b  = (u16*)  alloc((size_t)4096 * cD * 2);           // 8.4MB
  u16*   Wcat   = (u16*)  alloc((size_t)8704 * cD * 2);           // 17.8MB
  u16*   Woutb  = (u16*)  alloc((size_t)cV * cD * 2);             // 10.2MB
  float* bias01 = (float*)alloc(4096 * 4);
  float* qbuf   = (float*)alloc((size_t)cB * cA * 4);
  float* accbuf = (float*)alloc((size_t)cB * 8 * 512 * 4);        // 512KB
  float* lpart  = (float*)alloc((size_t)cB * 8 * 4);
  u16*   att_bf = (u16*)  alloc((size_t)cB * cE * 2);
  float* g0buf  = (float*)alloc((size_t)2 * cB * 4096 * 4);
  float* hh1buf = (float*)alloc((size_t)cB * 4096 * 4);
  u16*   z0bf   = (u16*)  alloc((size_t)cB * cD * 2);
  float* c0     = (float*)alloc((size_t)2 * cB * cD * 4);
  float* c1     = (float*)alloc((size_t)2 * cB * cD * 4);
  float* pmax   = (float*)alloc((size_t)cNS * cB * 40 * 4);
  float* psum   = (float*)alloc((size_t)cNS * cB * 40 * 4);
  int*   pai    = (int*)  alloc((size_t)cNS * cB * 40 * 4);
  float* tgtl   = (float*)alloc((size_t)cNS * cB * 4);
  float* cestep = (float*)alloc((size_t)cNS * 2 * 4);

  k_init<<<64, 256, 0, stream>>>(bar, qbuf, c0, c1, z1all);
  k_cvt<<<2048, 256, 0, stream>>>(hpad, hpadM, cB * cT * cE / 4);
  k_cvt8I<<<1024, 256, 0, stream>>>(hpad, ph8, cB * cT * 64);
  k_cvt<<<2048, 256, 0, stream>>>(embed, embb, cV * cD / 4);
  k_cvt<<<1024, 256, 0, stream>>>(Whh1, Whh1b, 4096 * cD / 4);
  k_cvt<<<2048, 256, 0, stream>>>(Wout, Woutb, cV * cD / 4);
  k_slice<<<1024, 256, 0, stream>>>(Wih0, Wih0m, 4096 * cD, 10, 1536, 0);
  // Wcat = [Wih1' (perm) | Whh0 | WdecT]
  k_permW<<<512, 256, 0, stream>>>(Wih1, Wcat, 4096 * cD, 10, 1024, 0);
  k_cvt<<<1024, 256, 0, stream>>>(Whh0, Wcat + (size_t)4096 * cD, 4096 * cD / 4);
  k_transp<<<512, 256, 0, stream>>>(Wdec, Wcat + (size_t)8192 * cD, cA * cD, 10, cA);
  // Wa' = perm rows of Wih0[:, 1024:1536]
  k_permW<<<512, 256, 0, stream>>>(Wih0, Wap, 4096 * cE, 9, 1536, 1024);
  k_transp<<<256, 256, 0, stream>>>(Wenc, WencT, cA * cE, 9, cA);
  k_bias<<<16, 256, 0, stream>>>(bih1, bhh1, bias01, 4096);
  k_pe<<<400, 256, 0, stream>>>(hpadM, WencT, ph8);
  k_eyproj<<<75, 256, 0, stream>>>(embb, ys, Wih0m, bih0, bhh0, eyproj, g0buf);

  LoopArgs la;
  la.hlen = hlen; la.ph8 = ph8; la.eyproj = eyproj;
  la.Wap = Wap; la.Whh1 = Whh1b; la.Wcat = Wcat;
  la.vatt = vatt; la.bias01 = bias01;
  la.q = qbuf; la.accbuf = accbuf; la.lpart = lpart; la.att_bf = att_bf;
  la.g0buf = g0buf; la.hh1buf = hh1buf; la.z0bf = z0bf;
  la.c0 = c0; la.c1 = c1; la.z1all = z1all; la.bar = bar;
  k_loop<<<NBLK, 512, 0, stream>>>(la);

  k_ce1<<<1200, 256, 0, stream>>>(z1all, Woutb, bout, ys, pmax, psum, pai, tgtl);
  k_ce2<<<cNS, 64, 0, stream>>>(pmax, psum, pai, tgtl, ys, cestep);
  k_ce3<<<1, 256, 0, stream>>>(cestep, (float*)d_out);
}

// Round 3
// 8235.259 us; speedup vs baseline: 2.1479x; 1.6163x over previous
//
#include <hip/hip_runtime.h>

// ---------------------------------------------------------------------------
// Decoder_60868276519063: attention-LSTM decoder forward (loss, acc)
// B=32 T=800 E=512 D=1024 V=5000 L=149 (150 steps) A=512
// Round 3: LDS-resident attention operands (102KB/CU, persistent), fp8 MFMA
// GEMVs (weights x16, acts x8), atomicAdd softmax combine, 3 barriers/step.
// ---------------------------------------------------------------------------

typedef unsigned short u16;
typedef unsigned char u8;
typedef long long i64;
typedef float f32x4 __attribute__((ext_vector_type(4)));
typedef float f32x2 __attribute__((ext_vector_type(2)));
typedef short s16x8 __attribute__((ext_vector_type(8)));

constexpr int cB = 32, cT = 800, cE = 512, cD = 1024, cV = 5000, cL = 149,
              cNS = 150, cA = 512;
constexpr int SOS = 1, EOS = 2;
constexpr int NBLK = 256;
constexpr float DS = 1.0f / 128.0f;   // fp8 descale: W x16, x x8

__device__ __forceinline__ float bf2f(u16 x){
  union { unsigned u; float f; } v; v.u = ((unsigned)x) << 16; return v.f;
}
__device__ __forceinline__ u16 f2bf(float f){
  union { float f; unsigned u; } v; v.f = f;
  unsigned r = v.u + 0x7FFFu + ((v.u >> 16) & 1u);
  return (u16)(r >> 16);
}
__device__ __forceinline__ float frcp(float x){ return __builtin_amdgcn_rcpf(x); }
__device__ __forceinline__ float fsigm(float x){ return frcp(1.f + __expf(-x)); }
__device__ __forceinline__ float ftanh(float x){
  float u = __expf(2.f * x);
  return 1.f - 2.f * frcp(u + 1.f);
}
__device__ __forceinline__ f32x4 MFMA(s16x8 a, s16x8 b, f32x4 c){
  return __builtin_amdgcn_mfma_f32_16x16x32_bf16(a, b, c, 0, 0, 0);
}
__device__ __forceinline__ f32x4 MFMA8(i64 a, i64 b, f32x4 c){
  return __builtin_amdgcn_mfma_f32_16x16x32_fp8_fp8(a, b, c, 0, 0, 0);
}
__device__ __forceinline__ s16x8 LD8(const u16* p){ return *(const s16x8*)p; }
__device__ __forceinline__ u8 f2fp8(float x){
  return (u8)(__builtin_amdgcn_cvt_pk_fp8_f32(x, x, 0, false) & 0xFF);
}
__device__ __forceinline__ unsigned pk4(float a, float b, float c, float d){
  unsigned w = (unsigned)__builtin_amdgcn_cvt_pk_fp8_f32(a, b, 0, false);
  w = (unsigned)__builtin_amdgcn_cvt_pk_fp8_f32(c, d, (int)w, true);
  return w;
}
__device__ __forceinline__ void unpack8(unsigned lo, unsigned hi, float* o){
  f32x2 a = __builtin_amdgcn_cvt_pk_f32_fp8((int)lo, false);
  f32x2 b = __builtin_amdgcn_cvt_pk_f32_fp8((int)lo, true);
  f32x2 c = __builtin_amdgcn_cvt_pk_f32_fp8((int)hi, false);
  f32x2 d = __builtin_amdgcn_cvt_pk_f32_fp8((int)hi, true);
  o[0]=a[0]; o[1]=a[1]; o[2]=b[0]; o[3]=b[1];
  o[4]=c[0]; o[5]=c[1]; o[6]=d[0]; o[7]=d[1];
}

// ------------------------------- prologue ----------------------------------
__global__ void k_init(int* bar, float* q, float* c0, float* c1, u8* z1f8,
                       float* att_acc, float* att_l){
  int i = blockIdx.x * blockDim.x + threadIdx.x, n = gridDim.x * blockDim.x;
  for (int k = i; k < 512; k += n) bar[k] = 0;
  for (int k = i; k < cB * cA; k += n) q[k] = 0.f;
  for (int k = i; k < 2 * cB * cD; k += n){ c0[k] = 0.f; c1[k] = 0.f; }
  for (int k = i; k < cB * cD / 4; k += n) ((unsigned*)z1f8)[k] = 0;
  for (int k = i; k < cB * cE; k += n) att_acc[k] = 0.f;
  for (int k = i; k < cB; k += n) att_l[k] = 0.f;
}

__global__ void k_cvt(const float* __restrict__ s, u16* __restrict__ d, int n4){
  int i = blockIdx.x * blockDim.x + threadIdx.x, st = gridDim.x * blockDim.x;
  for (int k = i; k < n4; k += st){
    float4 v = ((const float4*)s)[k];
    ushort4 o; o.x = f2bf(v.x); o.y = f2bf(v.y); o.z = f2bf(v.z); o.w = f2bf(v.w);
    ((ushort4*)d)[k] = o;
  }
}

// hpad -> fp8 h-half of interleaved ph8 rows: [grp*16+8 .. +15]
__global__ void k_cvt8I(const float* __restrict__ s, u8* __restrict__ d, int n){
  int i = blockIdx.x * blockDim.x + threadIdx.x, st = gridDim.x * blockDim.x;
  for (int k = i; k < n; k += st){
    int row = k >> 6, grp = k & 63;
    const float4* p = (const float4*)(s + (size_t)row * 512 + grp * 8);
    float4 v0 = p[0], v1 = p[1];
    unsigned lo = pk4(v0.x, v0.y, v0.z, v0.w);
    unsigned hi = pk4(v1.x, v1.y, v1.z, v1.w);
    *(uint2*)(d + (size_t)row * 1024 + grp * 16 + 8) = make_uint2(lo, hi);
  }
}

__global__ void k_slice(const float* __restrict__ s, u16* __restrict__ d, int n,
                        int cshift, int srcld, int coff){
  int i = blockIdx.x * blockDim.x + threadIdx.x, st = gridDim.x * blockDim.x;
  int cmask = (1 << cshift) - 1;
  for (int k = i; k < n; k += st){
    int r = k >> cshift, c = k & cmask;
    d[k] = f2bf(s[(size_t)r * srcld + coff + c]);
  }
}

__global__ void k_transp(const float* __restrict__ s, u16* __restrict__ d, int n,
                         int rshift, int csrc){
  int i = blockIdx.x * blockDim.x + threadIdx.x, st = gridDim.x * blockDim.x;
  int mask = (1 << rshift) - 1;
  for (int k = i; k < n; k += st){
    int dd = k & mask, a = k >> rshift;
    d[k] = f2bf(s[(size_t)dd * csrc + a]);
  }
}

__global__ void k_bias(const float* a, const float* b, float* o, int n){
  int i = blockIdx.x * blockDim.x + threadIdx.x, st = gridDim.x * blockDim.x;
  for (int k = i; k < n; k += st) o[k] = a[k] + b[k];
}

// fp8 weight convert, x16 scale, row-permuted: dst row R=j*32+jj, jj=g*8+c
// <-> orig row g*1024 + j*8 + c
__global__ void k_wf8perm(const float* __restrict__ s, u8* __restrict__ d,
                          int n4, int kshift, int srcld, int coff){
  int i = blockIdx.x * blockDim.x + threadIdx.x, st = gridDim.x * blockDim.x;
  int kmask = (1 << kshift) - 1;
  for (int k = i; k < n4; k += st){
    int flat = k * 4;
    int R = flat >> kshift, kk = flat & kmask;
    int j = R >> 5, jj = R & 31, g = jj >> 3, c = jj & 7;
    const float* p = s + (size_t)(g * 1024 + j * 8 + c) * srcld + coff + kk;
    ((unsigned*)d)[k] = pk4(p[0]*16.f, p[1]*16.f, p[2]*16.f, p[3]*16.f);
  }
}

__global__ void k_wf8(const float* __restrict__ s, u8* __restrict__ d, int n4){
  int i = blockIdx.x * blockDim.x + threadIdx.x, st = gridDim.x * blockDim.x;
  for (int k = i; k < n4; k += st){
    float4 v = ((const float4*)s)[k];
    ((unsigned*)d)[k] = pk4(v.x*16.f, v.y*16.f, v.z*16.f, v.w*16.f);
  }
}

// WdecT fp8: dst[a][dd] = Wdec[dd][a] * 16, dst [512][1024]
__global__ void k_wf8t(const float* __restrict__ s, u8* __restrict__ d, int n4){
  int i = blockIdx.x * blockDim.x + threadIdx.x, st = gridDim.x * blockDim.x;
  for (int k = i; k < n4; k += st){
    int flat = k * 4;
    int a = flat >> 10, dd = flat & 1023;
    ((unsigned*)d)[k] = pk4(s[(size_t)(dd+0)*512 + a]*16.f,
                            s[(size_t)(dd+1)*512 + a]*16.f,
                            s[(size_t)(dd+2)*512 + a]*16.f,
                            s[(size_t)(dd+3)*512 + a]*16.f);
  }
}

// ey[r][:] = embb[tok(r)][:]  (bf16 gather), r = s*32+b
__global__ void k_gather(const u16* __restrict__ embb, const int* __restrict__ ys,
                         u16* __restrict__ ey, int n16){
  int i = blockIdx.x * blockDim.x + threadIdx.x, st = gridDim.x * blockDim.x;
  for (int k = i; k < n16; k += st){
    int r = k >> 7, seg = k & 127;
    int s = r >> 5, b = r & 31;
    int tok = (s == 0) ? SOS : ys[b * cL + (s - 1)];
    ((uint4*)ey)[(size_t)r * 128 + seg] =
        ((const uint4*)embb)[(size_t)tok * 128 + seg];
  }
}

// pe GEMM: [25600x512] @ WencT[512 a][512 e]^T -> fp8 into ph8 pe-half
__global__ __launch_bounds__(512, 1) void k_pe2(const u16* __restrict__ A,
    const u16* __restrict__ Bw, u8* __restrict__ ph8){
  int tid = threadIdx.x, w = tid >> 6, l = tid & 63;
  int col = l & 15, kin = 8 * (l >> 4);
  int mw = w >> 2, nw = w & 3;
  int m0 = blockIdx.x * 128 + mw * 64;
  int n0 = nw * 128;
  f32x4 acc[4][8] = {};
  for (int kc = 0; kc < 16; ++kc){
    int k = kc * 32 + kin;
    s16x8 af[4], bf[8];
    #pragma unroll
    for (int i = 0; i < 4; ++i) af[i] = LD8(A + (size_t)(m0 + i*16 + col)*512 + k);
    #pragma unroll
    for (int j = 0; j < 8; ++j) bf[j] = LD8(Bw + (size_t)(n0 + j*16 + col)*512 + k);
    #pragma unroll
    for (int i = 0; i < 4; ++i)
      #pragma unroll
      for (int j = 0; j < 8; ++j) acc[i][j] = MFMA(af[i], bf[j], acc[i][j]);
  }
  int hi4 = (l >> 4) * 4;
  #pragma unroll
  for (int i = 0; i < 4; ++i)
    #pragma unroll
    for (int j = 0; j < 8; ++j){
      int a0 = n0 + j * 16 + col;
      size_t boff = ((size_t)(a0 >> 3) << 4) + (a0 & 7);
      #pragma unroll
      for (int r = 0; r < 4; ++r){
        int row = m0 + i * 16 + hi4 + r;
        ph8[(size_t)row * 1024 + boff] = f2fp8(acc[i][j][r]);
      }
    }
}

// eyproj GEMM: ey[4800x1024] @ Wih0m[4096x1024]^T + biases -> bf16 (+g0 f32)
__global__ __launch_bounds__(512, 1) void k_ey2(const u16* __restrict__ ey,
    const u16* __restrict__ Wm, const float* __restrict__ bih0,
    const float* __restrict__ bhh0, u16* __restrict__ eyproj,
    float* __restrict__ g0buf){
  int tid = threadIdx.x, w = tid >> 6, l = tid & 63;
  int col = l & 15, kin = 8 * (l >> 4);
  int mw = w >> 2, nw = w & 3;
  int m0 = blockIdx.x * 128 + mw * 64;
  int n0 = blockIdx.y * 512 + nw * 128;
  f32x4 acc[4][8] = {};
  for (int kc = 0; kc < 32; ++kc){
    int k = kc * 32 + kin;
    s16x8 af[4], bf[8];
    #pragma unroll
    for (int i = 0; i < 4; ++i){
      int ar = m0 + i * 16 + col; ar = (ar < 4800) ? ar : 0;
      af[i] = LD8(ey + (size_t)ar * 1024 + k);
    }
    #pragma unroll
    for (int j = 0; j < 8; ++j) bf[j] = LD8(Wm + (size_t)(n0 + j*16 + col)*1024 + k);
    #pragma unroll
    for (int i = 0; i < 4; ++i)
      #pragma unroll
      for (int j = 0; j < 8; ++j) acc[i][j] = MFMA(af[i], bf[j], acc[i][j]);
  }
  int hi4 = (l >> 4) * 4;
  #pragma unroll
  for (int i = 0; i < 4; ++i)
    #pragma unroll
    for (int j = 0; j < 8; ++j){
      int jc = n0 + j * 16 + col;
      float bj = bih0[jc] + bhh0[jc];
      #pragma unroll
      for (int r = 0; r < 4; ++r){
        int row = m0 + i * 16 + hi4 + r;
        if (row < 4800){
          float val = acc[i][j][r] + bj;
          eyproj[(size_t)row * 4096 + jc] = f2bf(val);
          if (row < 32) g0buf[(size_t)row * 4096 + jc] = val;
        }
      }
    }
}

// ------------------------------ main loop ----------------------------------
struct LoopArgs {
  const int* hlen;
  const u8* ph8;
  const u16* eyproj;
  const u8* Wapf8; const u8* Whh1f8; const u8* Wih1f8; const u8* Whh0f8;
  const u8* WdecTf8;
  const float* vatt; const float* bias01;
  float* q; float* att_acc; float* att_l;
  float* g0buf; float* hh1buf; u8* z0f8; u8* z1f8;
  float* c0; float* c1; u16* z1all;
  int* bar;
};

struct P1Lds { float red[8][512]; float ls[8]; };
struct GvLds { u8 x[33280]; float acc[8][2][16][16]; };   // x: 32 x SP(<=1040)
union LoopLds { P1Lds p1; GvLds gv; };

// store-only flag barrier: flags[0..255], release words at 256 + g*16
__device__ __forceinline__ void gbar(int* bar, int blk, int target){
  __syncthreads();
  if (threadIdx.x == 0){
    __threadfence();
    __hip_atomic_store(&bar[blk], target, __ATOMIC_RELAXED, __HIP_MEMORY_SCOPE_AGENT);
  }
  if (blk == NBLK - 1){
    if (threadIdx.x < NBLK){
      while (__hip_atomic_load(&bar[threadIdx.x], __ATOMIC_RELAXED,
                               __HIP_MEMORY_SCOPE_AGENT) < target)
        __builtin_amdgcn_s_sleep(1);
    }
    __syncthreads();
    if (threadIdx.x < 8){
      __threadfence();
      __hip_atomic_store(&bar[256 + threadIdx.x * 16], target, __ATOMIC_RELAXED,
                         __HIP_MEMORY_SCOPE_AGENT);
    }
  }
  if (threadIdx.x == 0){
    int* rel = &bar[256 + (blk >> 5) * 16];
    while (__hip_atomic_load(rel, __ATOMIC_RELAXED,
                             __HIP_MEMORY_SCOPE_AGENT) < target)
      __builtin_amdgcn_s_sleep(1);
    __threadfence();
  }
  __syncthreads();
}

// stage att_acc (f32, normalize by att_l, x8) -> fp8 LDS x[32][512], SP=528
__device__ __forceinline__ void stage_att(LoopLds& L, const float* att_acc,
                                          const float* att_l, int tid){
  int r = tid >> 4, c0 = (tid & 15) * 32;
  float sc = 8.0f / att_l[r];
  const float4* src = (const float4*)(att_acc + r * 512 + c0);
  unsigned wd[8];
  #pragma unroll
  for (int i = 0; i < 8; ++i){
    float4 f = src[i];
    wd[i] = pk4(f.x * sc, f.y * sc, f.z * sc, f.w * sc);
  }
  uint4* dst = (uint4*)&L.gv.x[r * 528 + c0];
  dst[0] = make_uint4(wd[0], wd[1], wd[2], wd[3]);
  dst[1] = make_uint4(wd[4], wd[5], wd[6], wd[7]);
}

// stage fp8 z[32][1024] -> LDS x, SP=1040
__device__ __forceinline__ void stage_z(LoopLds& L, const u8* zf8, int tid){
  int r = tid >> 4, c0 = (tid & 15) * 64;
  const uint4* src = (const uint4*)(zf8 + (size_t)r * 1024 + c0);
  uint4* dst = (uint4*)&L.gv.x[r * 1040 + c0];
  #pragma unroll
  for (int i = 0; i < 4; ++i) dst[i] = src[i];
}

// block GEMV fp8: out[32][NR] = x[32][K] @ W[NR][K]^T, acc in LDS.
// waves: nt = w/KH (n-tile of 16), kh = w%KH (K-slice). acc[w][mt][16][16].
template<int NR, int K>
__device__ __forceinline__ void gemv_f8(const u8* __restrict__ wb,
                                        LoopLds& L, int tid){
  constexpr int NT = NR / 16, KH = 8 / NT, KB = K / KH, SP = K + 16;
  const int w = tid >> 6, l = tid & 63;
  const int col = l & 15, kin = 8 * (l >> 4);
  const int nt = w / KH, kh = w % KH;
  const u8* wr = wb + (size_t)(nt * 16 + col) * K + kh * KB + kin;
  const u8* xr = &L.gv.x[col * SP + kh * KB + kin];
  f32x4 a0 = {0.f,0.f,0.f,0.f}, a1 = {0.f,0.f,0.f,0.f};
  #pragma unroll
  for (int kc = 0; kc < KB / 32; ++kc){
    i64 wv = *(const i64*)(wr + kc * 32);
    i64 x0 = *(const i64*)(xr + kc * 32);
    i64 x1 = *(const i64*)(xr + 16 * SP + kc * 32);
    a0 = MFMA8(x0, wv, a0);
    a1 = MFMA8(x1, wv, a1);
  }
  const int hi4 = (l >> 4) * 4;
  #pragma unroll
  for (int r = 0; r < 4; ++r){
    L.gv.acc[w][0][hi4 + r][col] = a0[r];
    L.gv.acc[w][1][hi4 + r][col] = a1[r];
  }
}

__global__ __launch_bounds__(512, 1) void k_loop(LoopArgs g_){
  __shared__ __align__(16) LoopLds L;
  __shared__ __align__(16) u8 ph8_lds[100 * 1024];
  const int blk = blockIdx.x, tid = threadIdx.x;
  const int w = tid >> 6, l = tid & 63;
  const int b_att = blk >> 3, oct = blk & 7;
  const int hl = g_.hlen[b_att];
  const int t0 = oct * 100;
  const int t1 = (t0 + 100 < hl) ? t0 + 100 : hl;
  const int nrow = t1 - t0;
  float vv[8];
  #pragma unroll
  for (int i = 0; i < 8; ++i) vv[i] = g_.vatt[l * 8 + i];
  // persistent LDS copy of this block's attention chunk
  for (int idx = tid; idx < nrow * 64; idx += 512){
    int rr = idx >> 6, gg = idx & 63;
    *(uint4*)&ph8_lds[rr * 1024 + gg * 16] =
        *(const uint4*)(g_.ph8 + ((size_t)b_att * cT + t0 + rr) * 1024 + gg * 16);
  }
  __syncthreads();
  int target = 0;
  for (int s = 0; s < cNS; ++s){
    const int p = s & 1;
    // ======== A: attention (LDS-resident, no-max softmax, atomics) ========
    if (nrow > 0){
      float qv[8];
      const float* qb = g_.q + b_att * cA + l * 8;
      #pragma unroll
      for (int i = 0; i < 8; ++i) qv[i] = qb[i];
      float acc8[8] = {0.f,0.f,0.f,0.f,0.f,0.f,0.f,0.f};
      float lsum = 0.f;
      for (int t = t0 + w; t < t1; t += 8){
        uint4 v = *(const uint4*)&ph8_lds[(t - t0) * 1024 + l * 16];
        float x[8]; unpack8(v.x, v.y, x);
        float e_ = 0.f;
        #pragma unroll
        for (int i = 0; i < 8; ++i) e_ += vv[i] * ftanh(x[i] + qv[i]);
        #pragma unroll
        for (int m = 1; m < 64; m <<= 1) e_ += __shfl_xor(e_, m, 64);
        float wt = __expf(e_);          // |e| <= sum|v_att| ~ 8.2
        lsum += wt;
        float h[8]; unpack8(v.z, v.w, h);
        #pragma unroll
        for (int i = 0; i < 8; ++i) acc8[i] = fmaf(wt, h[i], acc8[i]);
      }
      *(f32x4*)&L.p1.red[w][l * 8]     = *(f32x4*)&acc8[0];
      *(f32x4*)&L.p1.red[w][l * 8 + 4] = *(f32x4*)&acc8[4];
      if (l == 0) L.p1.ls[w] = lsum;
      __syncthreads();
      float vsum = 0.f;
      #pragma unroll
      for (int ww = 0; ww < 8; ++ww) vsum += L.p1.red[ww][tid];
      atomicAdd(&g_.att_acc[b_att * cE + tid], vsum);
      if (tid == 0){
        float ls = 0.f;
        #pragma unroll
        for (int i = 0; i < 8; ++i) ls += L.p1.ls[i];
        atomicAdd(&g_.att_l[b_att], ls);
      }
    }
    gbar(g_.bar, blk, ++target);
    // ======== B: Wa GEMV + LSTM0 (blk<128) | hh1 GEMV (blk>=128) ==========
    if (blk < 128){
      stage_att(L, g_.att_acc, g_.att_l, tid);
      __syncthreads();
      gemv_f8<32, 512>(g_.Wapf8 + (size_t)blk * 32 * 512, L, tid);
      __syncthreads();
      if (tid < 256){
        int b = tid >> 3, dc = tid & 7, d = blk * 8 + dc;
        int mt = b >> 4, rr = b & 15;
        float gate[4];
        #pragma unroll
        for (int g = 0; g < 4; ++g){
          int jj = g * 8 + dc;
          float v = 0.f;
          #pragma unroll
          for (int kh = 0; kh < 4; ++kh)
            v += L.gv.acc[(jj >> 4) * 4 + kh][mt][rr][jj & 15];
          gate[g] = v * DS + g_.g0buf[(size_t)p * cB * 4096 + b * 4096 + g * 1024 + d];
        }
        float c = fsigm(gate[1]) * g_.c0[(size_t)p * cB * cD + b * cD + d] +
                  fsigm(gate[0]) * ftanh(gate[2]);
        float z = fsigm(gate[3]) * ftanh(c);
        g_.c0[(size_t)(p ^ 1) * cB * cD + b * cD + d] = c;
        g_.z0f8[b * cD + d] = f2fp8(z * 8.f);
      }
    } else {
      stage_z(L, g_.z1f8, tid);
      __syncthreads();
      gemv_f8<32, 1024>(g_.Whh1f8 + (size_t)(blk - 128) * 32 * 1024, L, tid);
      __syncthreads();
      const int jb = (blk - 128) * 32;
      #pragma unroll
      for (int it = 0; it < 2; ++it){
        int idx = it * 512 + tid;
        int b = idx >> 5, jj = idx & 31;
        int mt = b >> 4, rr = b & 15;
        float v = 0.f;
        #pragma unroll
        for (int kh = 0; kh < 4; ++kh)
          v += L.gv.acc[(jj >> 4) * 4 + kh][mt][rr][jj & 15];
        g_.hh1buf[b * 4096 + jb + jj] = v * DS + g_.bias01[jb + jj];
      }
    }
    gbar(g_.bar, blk, ++target);
    // ======== C: Wih1+LSTM1 | Whh0->g0 | Wdec->q | zero att ===============
    if (blk < 128){
      stage_z(L, g_.z0f8, tid);
      __syncthreads();
      gemv_f8<32, 1024>(g_.Wih1f8 + (size_t)blk * 32 * 1024, L, tid);
      __syncthreads();
      if (tid < 256){
        int b = tid >> 3, dc = tid & 7, d = blk * 8 + dc;
        int mt = b >> 4, rr = b & 15;
        float gate[4];
        #pragma unroll
        for (int g = 0; g < 4; ++g){
          int jj = g * 8 + dc;
          float v = 0.f;
          #pragma unroll
          for (int kh = 0; kh < 4; ++kh)
            v += L.gv.acc[(jj >> 4) * 4 + kh][mt][rr][jj & 15];
          gate[g] = v * DS + g_.hh1buf[b * 4096 + g * 1024 + d];
        }
        float c = fsigm(gate[1]) * g_.c1[(size_t)p * cB * cD + b * cD + d] +
                  fsigm(gate[0]) * ftanh(gate[2]);
        float z = fsigm(gate[3]) * ftanh(c);
        g_.c1[(size_t)(p ^ 1) * cB * cD + b * cD + d] = c;
        g_.z1all[((size_t)s + 1) * cB * cD + b * cD + d] = f2bf(z);
        g_.z1f8[b * cD + d] = f2fp8(z * 8.f);
      }
    } else if (blk < 192){
      stage_z(L, g_.z0f8, tid);
      __syncthreads();
      gemv_f8<64, 1024>(g_.Whh0f8 + (size_t)(blk - 128) * 64 * 1024, L, tid);
      __syncthreads();
      if (s < cNS - 1){
        const int jb = (blk - 128) * 64;
        #pragma unroll
        for (int it = 0; it < 4; ++it){
          int idx = it * 512 + tid;
          int b = idx >> 6, jj = idx & 63;
          int mt = b >> 4, rr = b & 15;
          float v = 0.f;
          #pragma unroll
          for (int kh = 0; kh < 2; ++kh)
            v += L.gv.acc[(jj >> 4) * 2 + kh][mt][rr][jj & 15];
          g_.g0buf[(size_t)(p ^ 1) * cB * 4096 + b * 4096 + jb + jj] =
              v * DS + bf2f(g_.eyproj[(((size_t)s + 1) * cB + b) * 4096 + jb + jj]);
        }
      }
    } else if (blk < 208){
      stage_z(L, g_.z0f8, tid);
      __syncthreads();
      gemv_f8<32, 1024>(g_.WdecTf8 + (size_t)(blk - 192) * 32 * 1024, L, tid);
      __syncthreads();
      if (s < cNS - 1){
        const int jb = (blk - 192) * 32;
        #pragma unroll
        for (int it = 0; it < 2; ++it){
          int idx = it * 512 + tid;
          int b = idx >> 5, jj = idx & 31;
          int mt = b >> 4, rr = b & 15;
          float v = 0.f;
          #pragma unroll
          for (int kh = 0; kh < 4; ++kh)
            v += L.gv.acc[(jj >> 4) * 4 + kh][mt][rr][jj & 15];
          g_.q[b * cA + jb + jj] = v * DS;
        }
      }
    } else if (blk == 208){
      for (int i = tid; i < cB * cE; i += 512) g_.att_acc[i] = 0.f;
      if (tid < 32) g_.att_l[tid] = 0.f;
    }
    gbar(g_.bar, blk, ++target);
  }
}

// ------------------------------ epilogue -----------------------------------
__global__ __launch_bounds__(256) void k_ce1(const u16* __restrict__ z1all,
    const u16* __restrict__ Woutb, const float* __restrict__ bout,
    const int* __restrict__ ys, float* __restrict__ pmax, float* __restrict__ psum,
    int* __restrict__ pai, float* __restrict__ tgtl){
  int blk = blockIdx.x;
  int sc = blk / 40, vc = blk % 40;
  int tid = threadIdx.x, w = tid >> 6, l = tid & 63;
  int kin = 8 * (l >> 4), col = l & 15;
  int v0 = vc * 128 + w * 32;
  int vA = v0 + col, vB = v0 + 16 + col;
  float boA = (vA < cV) ? bout[vA] : 0.f;
  float boB = (vB < cV) ? bout[vB] : 0.f;
  const u16* wrA = Woutb + (size_t)((vA < cV) ? vA : cV - 1) * cD;
  const u16* wrB = Woutb + (size_t)((vB < cV) ? vB : cV - 1) * cD;
  __shared__ int tgt_sh[32];
  __shared__ float rsm[4][32], rss[4][32];
  __shared__ int rsi[4][32];
  for (int si = 0; si < 5; ++si){
    int s = sc * 5 + si;
    if (tid < 32) tgt_sh[tid] = (s < cL) ? ys[tid * cL + s] : EOS;
    __syncthreads();
    const u16* z1s = z1all + ((size_t)s + 1) * cB * cD;
    f32x4 aA0 = {0.f,0.f,0.f,0.f}, aA1 = {0.f,0.f,0.f,0.f};
    f32x4 aB0 = {0.f,0.f,0.f,0.f}, aB1 = {0.f,0.f,0.f,0.f};
    for (int kc = 0; kc < 32; ++kc){
      int k = kc * 32 + kin;
      s16x8 x0 = LD8(z1s + (size_t)col * cD + k);
      s16x8 x1 = LD8(z1s + (size_t)(16 + col) * cD + k);
      s16x8 bA = LD8(wrA + k);
      s16x8 bB = LD8(wrB + k);
      aA0 = MFMA(x0, bA, aA0); aA1 = MFMA(x1, bA, aA1);
      aB0 = MFMA(x0, bB, aB0); aB1 = MFMA(x1, bB, aB1);
    }
    #pragma unroll
    for (int mt = 0; mt < 2; ++mt)
    #pragma unroll
    for (int reg = 0; reg < 4; ++reg){
      int row = mt * 16 + (l >> 4) * 4 + reg;
      float va = (mt ? aA1[reg] : aA0[reg]) + boA; if (vA >= cV) va = -1e30f;
      float vb = (mt ? aB1[reg] : aB0[reg]) + boB; if (vB >= cV) vb = -1e30f;
      int tg = tgt_sh[row];
      if (vA == tg) tgtl[(size_t)s * cB + row] = va;
      if (vB == tg) tgtl[(size_t)s * cB + row] = vb;
      float mx = fmaxf(va, vb);
      int ix = (va >= vb) ? vA : vB;
      #pragma unroll
      for (int m = 1; m < 16; m <<= 1){
        float om = __shfl_xor(mx, m, 64);
        int oi = __shfl_xor(ix, m, 64);
        if (om > mx || (om == mx && oi < ix)){ mx = om; ix = oi; }
      }
      float se = __expf(va - mx) + __expf(vb - mx);
      #pragma unroll
      for (int m = 1; m < 16; m <<= 1) se += __shfl_xor(se, m, 64);
      if ((l & 15) == 0){ rsm[w][row] = mx; rss[w][row] = se; rsi[w][row] = ix; }
    }
    __syncthreads();
    if (tid < 32){
      int b = tid;
      float gm = -1e30f;
      #pragma unroll
      for (int w2 = 0; w2 < 4; ++w2) gm = fmaxf(gm, rsm[w2][b]);
      float gs = 0.f; float bv = -1e30f; int bix = 0x7fffffff;
      #pragma unroll
      for (int w2 = 0; w2 < 4; ++w2){
        gs += rss[w2][b] * __expf(rsm[w2][b] - gm);
        float v = rsm[w2][b]; int ii = rsi[w2][b];
        if (v > bv || (v == bv && ii < bix)){ bv = v; bix = ii; }
      }
      size_t o = ((size_t)s * cB + b) * 40 + vc;
      pmax[o] = gm; psum[o] = gs; pai[o] = bix;
    }
    __syncthreads();
  }
}

__global__ __launch_bounds__(64) void k_ce2(const float* __restrict__ pmax,
    const float* __restrict__ psum, const int* __restrict__ pai,
    const float* __restrict__ tgtl, const int* __restrict__ ys,
    float* __restrict__ cestep){
  int s = blockIdx.x, tid = threadIdx.x;
  float nll = 0.f, cor = 0.f;
  if (tid < 32){
    int b = tid;
    size_t o = ((size_t)s * cB + b) * 40;
    float gm = -1e30f;
    for (int c = 0; c < 40; ++c) gm = fmaxf(gm, pmax[o + c]);
    float gs = 0.f; float bv = -1e30f; int bix = 0x7fffffff;
    for (int c = 0; c < 40; ++c){
      gs += psum[o + c] * __expf(pmax[o + c] - gm);
      float v = pmax[o + c]; int ii = pai[o + c];
      if (v > bv || (v == bv && ii < bix)){ bv = v; bix = ii; }
    }
    nll = __logf(gs) + gm - tgtl[(size_t)s * cB + b];
    int tgt = (s < cL) ? ys[b * cL + s] : EOS;
    cor = (bix == tgt) ? 1.f : 0.f;
  }
  #pragma unroll
  for (int m = 1; m < 64; m <<= 1){
    nll += __shfl_xor(nll, m, 64); cor += __shfl_xor(cor, m, 64);
  }
  if (tid == 0){ cestep[s * 2] = nll; cestep[s * 2 + 1] = cor; }
}

__global__ __launch_bounds__(256) void k_ce3(const float* __restrict__ cestep,
                                             float* __restrict__ out){
  int tid = threadIdx.x;
  float nll = 0.f, cor = 0.f;
  for (int s = tid; s < cNS; s += 256){ nll += cestep[s * 2]; cor += cestep[s * 2 + 1]; }
  __shared__ float sn[4], sc_[4];
  int w = tid >> 6, l = tid & 63;
  #pragma unroll
  for (int m = 1; m < 64; m <<= 1){
    nll += __shfl_xor(nll, m, 64); cor += __shfl_xor(cor, m, 64);
  }
  if (l == 0){ sn[w] = nll; sc_[w] = cor; }
  __syncthreads();
  if (tid == 0){
    float a = sn[0] + sn[1] + sn[2] + sn[3];
    float b = sc_[0] + sc_[1] + sc_[2] + sc_[3];
    out[0] = a / (float)(cB * cNS) * (float)cL;
    out[1] = b / (float)(cB * cNS);
  }
}

// ------------------------------- host --------------------------------------
extern "C" void kernel_launch(void* const* d_in, const int* in_sizes, int n_in,
                              void* d_out, int out_size, void* d_ws, size_t ws_size,
                              hipStream_t stream){
  const float* hpad = (const float*)d_in[0];
  const int*   hlen = (const int*)d_in[1];
  const int*   ys   = (const int*)d_in[2];
  const float* embed= (const float*)d_in[3];
  const float* Wout = (const float*)d_in[4];
  const float* bout = (const float*)d_in[5];
  const float* Wenc = (const float*)d_in[6];
  const float* Wdec = (const float*)d_in[7];
  const float* vatt = (const float*)d_in[8];
  const float* Wih0 = (const float*)d_in[9];
  const float* bih0 = (const float*)d_in[10];
  const float* Whh0 = (const float*)d_in[11];
  const float* bhh0 = (const float*)d_in[12];
  const float* Wih1 = (const float*)d_in[13];
  const float* bih1 = (const float*)d_in[14];
  const float* Whh1 = (const float*)d_in[15];
  const float* bhh1 = (const float*)d_in[16];
  (void)in_sizes; (void)n_in; (void)out_size; (void)ws_size;

  char* base = (char*)d_ws;
  size_t off = 0;
  auto alloc = [&](size_t bytes) -> void* {
    void* r = base + off; off += (bytes + 255) & ~(size_t)255; return r;
  };
  int*   bar     = (int*)  alloc(512 * sizeof(int));
  u16*   hpadM   = (u16*)  alloc((size_t)cB * cT * cE * 2);
  u8*    ph8     = (u8*)   alloc((size_t)cB * cT * 1024);
  u16*   embb    = (u16*)  alloc((size_t)cV * cD * 2);
  u16*   ey      = (u16*)  alloc((size_t)cNS * cB * cD * 2);
  u16*   eyproj  = (u16*)  alloc((size_t)cNS * cB * 4096 * 2);
  u16*   z1all   = (u16*)  alloc((size_t)(cNS + 1) * cB * cD * 2);
  u16*   WencT   = (u16*)  alloc((size_t)cA * cE * 2);
  u16*   Wih0m   = (u16*)  alloc((size_t)4096 * cD * 2);
  u16*   Woutb   = (u16*)  alloc((size_t)cV * cD * 2);
  u8*    Wapf8   = (u8*)   alloc((size_t)4096 * 512);
  u8*    Wih1f8  = (u8*)   alloc((size_t)4096 * 1024);
  u8*    Whh1f8  = (u8*)   alloc((size_t)4096 * 1024);
  u8*    Whh0f8  = (u8*)   alloc((size_t)4096 * 1024);
  u8*    WdecTf8 = (u8*)   alloc((size_t)512 * 1024);
  float* bias01  = (float*)alloc(4096 * 4);
  float* qbuf    = (float*)alloc((size_t)cB * cA * 4);
  float* att_acc = (float*)alloc((size_t)cB * cE * 4);
  float* att_l   = (float*)alloc((size_t)cB * 4);
  float* g0buf   = (float*)alloc((size_t)2 * cB * 4096 * 4);
  float* hh1buf  = (float*)alloc((size_t)cB * 4096 * 4);
  u8*    z0f8    = (u8*)   alloc((size_t)cB * cD);
  u8*    z1f8    = (u8*)   alloc((size_t)cB * cD);
  float* c0      = (float*)alloc((size_t)2 * cB * cD * 4);
  float* c1      = (float*)alloc((size_t)2 * cB * cD * 4);
  float* pmax    = (float*)alloc((size_t)cNS * cB * 40 * 4);
  float* psum    = (float*)alloc((size_t)cNS * cB * 40 * 4);
  int*   pai     = (int*)  alloc((size_t)cNS * cB * 40 * 4);
  float* tgtl    = (float*)alloc((size_t)cNS * cB * 4);
  float* cestep  = (float*)alloc((size_t)cNS * 2 * 4);

  k_init<<<64, 256, 0, stream>>>(bar, qbuf, c0, c1, z1f8, att_acc, att_l);
  k_cvt<<<2048, 256, 0, stream>>>(hpad, hpadM, cB * cT * cE / 4);
  k_cvt8I<<<1024, 256, 0, stream>>>(hpad, ph8, cB * cT * 64);
  k_cvt<<<2048, 256, 0, stream>>>(embed, embb, cV * cD / 4);
  k_cvt<<<2048, 256, 0, stream>>>(Wout, Woutb, cV * cD / 4);
  k_slice<<<1024, 256, 0, stream>>>(Wih0, Wih0m, 4096 * cD, 10, 1536, 0);
  k_transp<<<256, 256, 0, stream>>>(Wenc, WencT, cA * cE, 9, cA);
  k_bias<<<16, 256, 0, stream>>>(bih1, bhh1, bias01, 4096);
  // fp8 weights (x16)
  k_wf8perm<<<512, 256, 0, stream>>>(Wih0, Wapf8, 4096 * 512 / 4, 9, 1536, 1024);
  k_wf8perm<<<1024, 256, 0, stream>>>(Wih1, Wih1f8, 4096 * 1024 / 4, 10, 1024, 0);
  k_wf8<<<1024, 256, 0, stream>>>(Whh1, Whh1f8, 4096 * 1024 / 4);
  k_wf8<<<1024, 256, 0, stream>>>(Whh0, Whh0f8, 4096 * 1024 / 4);
  k_wf8t<<<128, 256, 0, stream>>>(Wdec, WdecTf8, 512 * 1024 / 4);
  // batched projections
  k_gather<<<1200, 256, 0, stream>>>(embb, ys, ey, cNS * cB * 128);
  k_pe2<<<200, 512, 0, stream>>>(hpadM, WencT, ph8);
  k_ey2<<<dim3(38, 8), 512, 0, stream>>>(ey, Wih0m, bih0, bhh0, eyproj, g0buf);

  LoopArgs la;
  la.hlen = hlen; la.ph8 = ph8; la.eyproj = eyproj;
  la.Wapf8 = Wapf8; la.Whh1f8 = Whh1f8; la.Wih1f8 = Wih1f8;
  la.Whh0f8 = Whh0f8; la.WdecTf8 = WdecTf8;
  la.vatt = vatt; la.bias01 = bias01;
  la.q = qbuf; la.att_acc = att_acc; la.att_l = att_l;
  la.g0buf = g0buf; la.hh1buf = hh1buf; la.z0f8 = z0f8; la.z1f8 = z1f8;
  la.c0 = c0; la.c1 = c1; la.z1all = z1all; la.bar = bar;
  k_loop<<<NBLK, 512, 0, stream>>>(la);

  k_ce1<<<1200, 256, 0, stream>>>(z1all, Woutb, bout, ys, pmax, psum, pai, tgtl);
  k_ce2<<<cNS, 64, 0, stream>>>(pmax, psum, pai, tgtl, ys, cestep);
  k_ce3<<<1, 256, 0, stream>>>(cestep, (float*)d_out);
}